// Round 1
// baseline (850.027 us; speedup 1.0000x reference)
//
#include <hip/hip_runtime.h>
#include <math.h>

#define NN 50000
#define EE 800000
#define GG 1024
#define HIDD 128
#define NHEAD 4
#define EPTOT (EE + NN)
#define NEG_SLOPE 0.2f

__global__ void zero_kernel(float* __restrict__ p, int n) {
  int i = blockIdx.x * blockDim.x + threadIdx.x;
  if (i < n) p[i] = 0.f;
}

__global__ void count_kernel(const int* __restrict__ ei, int* __restrict__ deg) {
  int e = blockIdx.x * blockDim.x + threadIdx.x;
  if (e >= EPTOT) return;
  int d = (e < EE) ? ei[EE + e] : (e - EE);
  atomicAdd(&deg[d], 1);
}

__global__ __launch_bounds__(1024) void scan_kernel(const int* __restrict__ deg,
                                                    int* __restrict__ rowptr,
                                                    int* __restrict__ nxt) {
  __shared__ int ssum[1024];
  int t = threadIdx.x;
  const int chunk = (NN + 1023) >> 10;
  int b0 = t * chunk;
  int b1 = min(b0 + chunk, NN);
  int s = 0;
  for (int i = b0; i < b1; ++i) s += deg[i];
  ssum[t] = s;
  __syncthreads();
  for (int off = 1; off < 1024; off <<= 1) {
    int v = (t >= off) ? ssum[t - off] : 0;
    __syncthreads();
    ssum[t] += v;
    __syncthreads();
  }
  int run = (t == 0) ? 0 : ssum[t - 1];
  for (int i = b0; i < b1; ++i) {
    rowptr[i] = run;
    nxt[i] = run;
    run += deg[i];
  }
  if (t == 1023) rowptr[NN] = run;
}

__global__ void scatter_kernel(const int* __restrict__ ei, int* __restrict__ nxt,
                               int* __restrict__ colb) {
  int e = blockIdx.x * blockDim.x + threadIdx.x;
  if (e >= EPTOT) return;
  int s, d;
  if (e < EE) { s = ei[e]; d = ei[EE + e]; } else { s = e - EE; d = s; }
  int pos = atomicAdd(&nxt[d], 1);
  colb[pos] = s;
}

__device__ inline void fma4(float4& a, float s, const float4& b) {
  a.x += s * b.x; a.y += s * b.y; a.z += s * b.z; a.w += s * b.w;
}

// C = X[rows x 128] @ W[128 x 128], 32 rows per block, thread tile 4x4
__global__ __launch_bounds__(256) void gemm_kernel(const float* __restrict__ X,
                                                   const float* __restrict__ Wm,
                                                   float* __restrict__ Y, int nrows) {
  __shared__ float wsh[HIDD][HIDD];
  __shared__ float xsh[32][HIDD];
  int tid = threadIdx.x;
  float* wflat = &wsh[0][0];
  for (int i = tid * 4; i < HIDD * HIDD; i += 1024)
    *(float4*)(wflat + i) = *(const float4*)(Wm + i);
  int row0 = blockIdx.x * 32;
  float* xflat = &xsh[0][0];
  for (int i = tid * 4; i < 32 * HIDD; i += 1024) {
    int r = i >> 7, c = i & 127;
    float4 v = make_float4(0.f, 0.f, 0.f, 0.f);
    if (row0 + r < nrows) v = *(const float4*)(X + (size_t)(row0 + r) * HIDD + c);
    *(float4*)(xflat + i) = v;
  }
  __syncthreads();
  int rg = tid >> 5;  // 0..7 -> rows rg*4..+4
  int cg = tid & 31;  // cols cg*4..+4
  float4 acc[4];
#pragma unroll
  for (int i = 0; i < 4; ++i) acc[i] = make_float4(0.f, 0.f, 0.f, 0.f);
  for (int k = 0; k < HIDD; k += 4) {
    float4 wv[4];
#pragma unroll
    for (int j = 0; j < 4; ++j) wv[j] = *(float4*)&wsh[k + j][cg * 4];
#pragma unroll
    for (int i = 0; i < 4; ++i) {
      float4 xv = *(float4*)&xsh[rg * 4 + i][k];
      fma4(acc[i], xv.x, wv[0]);
      fma4(acc[i], xv.y, wv[1]);
      fma4(acc[i], xv.z, wv[2]);
      fma4(acc[i], xv.w, wv[3]);
    }
  }
#pragma unroll
  for (int i = 0; i < 4; ++i) {
    int r = row0 + rg * 4 + i;
    if (r < nrows) *(float4*)(Y + (size_t)r * HIDD + cg * 4) = acc[i];
  }
}

__global__ void edot_kernel(const float* __restrict__ Hm, const float* __restrict__ asrc,
                            const float* __restrict__ adst, float* __restrict__ esrc,
                            float* __restrict__ edst) {
  int gid = blockIdx.x * blockDim.x + threadIdx.x;
  if (gid >= NN * NHEAD) return;
  int node = gid >> 2, hd = gid & 3;
  const float* hp = Hm + (size_t)node * HIDD + hd * 32;
  const float* ap = asrc + hd * 32;
  const float* bp = adst + hd * 32;
  float s1 = 0.f, s2 = 0.f;
#pragma unroll
  for (int c = 0; c < 32; c += 4) {
    float4 hv = *(const float4*)(hp + c);
    float4 av = *(const float4*)(ap + c);
    float4 bv = *(const float4*)(bp + c);
    s1 += hv.x * av.x + hv.y * av.y + hv.z * av.z + hv.w * av.w;
    s2 += hv.x * bv.x + hv.y * bv.y + hv.z * bv.z + hv.w * bv.w;
  }
  esrc[gid] = s1;
  edst[gid] = s2;
}

// one 64-lane wave per dst node; lane owns channels 2l,2l+1 (head = l>>4)
__global__ __launch_bounds__(256) void agg_kernel(const float* __restrict__ Hm,
                                                  const float* __restrict__ esrc,
                                                  const float* __restrict__ edst,
                                                  const int* __restrict__ rowptr,
                                                  const int* __restrict__ colb,
                                                  const float* __restrict__ bias,
                                                  float* __restrict__ out) {
  int wid = (blockIdx.x * 256 + threadIdx.x) >> 6;
  int lane = threadIdx.x & 63;
  if (wid >= NN) return;
  int hd = lane >> 4;
  float ed = edst[wid * 4 + hd];
  int e0 = rowptr[wid], e1 = rowptr[wid + 1];
  float m = -1e30f, den = 0.f, ax = 0.f, ay = 0.f;
  const float* hbase = Hm + 2 * lane;
  for (int e = e0; e < e1; ++e) {
    int src = colb[e];
    float es = esrc[src * 4 + hd];
    float z = es + ed;
    z = (z > 0.f) ? z : NEG_SLOPE * z;
    float nm = fmaxf(m, z);
    float corr = __expf(m - nm);
    float p = __expf(z - nm);
    float2 hv = *(const float2*)(hbase + (size_t)src * HIDD);
    den = den * corr + p;
    ax = ax * corr + p * hv.x;
    ay = ay * corr + p * hv.y;
    m = nm;
  }
  float inv = 1.f / (den + 1e-16f);
  int c = 2 * lane;
  out[(size_t)wid * HIDD + c] = ax * inv + bias[c];
  out[(size_t)wid * HIDD + c + 1] = ay * inv + bias[c + 1];
}

__global__ __launch_bounds__(256) void bnstat_kernel(const float* __restrict__ X,
                                                     float* __restrict__ stat) {
  __shared__ float sh[256];
  int tid = threadIdx.x;
  int c = tid & 127;
  int half = tid >> 7;
  float s = 0.f, q = 0.f;
  for (int r = blockIdx.x * 2 + half; r < NN; r += gridDim.x * 2) {
    float v = X[(size_t)r * HIDD + c];
    s += v;
    q += v * v;
  }
  sh[tid] = s;
  __syncthreads();
  if (tid < 128) atomicAdd(&stat[c], s + sh[tid + 128]);
  __syncthreads();
  sh[tid] = q;
  __syncthreads();
  if (tid < 128) atomicAdd(&stat[128 + c], q + sh[tid + 128]);
}

__global__ void bnapply_kernel(float* __restrict__ X, const float* __restrict__ stat,
                               const float* __restrict__ gamma,
                               const float* __restrict__ beta) {
  int i = blockIdx.x * blockDim.x + threadIdx.x;
  if (i >= NN * HIDD) return;
  int c = i & 127;
  const float invN = 1.f / (float)NN;
  float mean = stat[c] * invN;
  float var = stat[128 + c] * invN - mean * mean;
  float scale = gamma[c] * rsqrtf(var + 1e-5f);
  float shift = beta[c] - mean * scale;
  float v = X[i] * scale + shift;
  X[i] = (v > 0.f) ? v : expm1f(v);
}

__global__ void pool_kernel(const float* __restrict__ X, const int* __restrict__ batch,
                            float* __restrict__ pooled, float* __restrict__ cnt) {
  int i = blockIdx.x * blockDim.x + threadIdx.x;
  if (i >= NN * HIDD) return;
  int node = i >> 7, c = i & 127;
  int g = batch[node];
  atomicAdd(&pooled[(size_t)g * HIDD + c], X[i]);
  if (c == 0) atomicAdd(&cnt[g], 1.f);
}

__global__ __launch_bounds__(256) void head_kernel(const float* __restrict__ pooled,
                                                   const float* __restrict__ cnt,
                                                   const float* __restrict__ w1,
                                                   const float* __restrict__ b1,
                                                   const float* __restrict__ w2,
                                                   const float* __restrict__ b2,
                                                   float* __restrict__ out) {
  int wid = (blockIdx.x * 256 + threadIdx.x) >> 6;
  int lane = threadIdx.x & 63;
  if (wid >= GG) return;
  float inv = 1.f / fmaxf(cnt[wid], 1.f);
  float acc = b1[lane];
  const float* pg = pooled + (size_t)wid * HIDD;
  for (int k = 0; k < HIDD; ++k) {
    acc += pg[k] * inv * w1[k * 64 + lane];
  }
  acc = fmaxf(acc, 0.f);
  float v = acc * w2[lane];
#pragma unroll
  for (int off = 32; off > 0; off >>= 1) v += __shfl_down(v, off);
  if (lane == 0) out[wid] = v + b2[0];
}

extern "C" void kernel_launch(void* const* d_in, const int* in_sizes, int n_in,
                              void* d_out, int out_size, void* d_ws, size_t ws_size,
                              hipStream_t stream) {
  const float* x    = (const float*)d_in[0];
  const int* ei     = (const int*)d_in[1];
  const int* batch  = (const int*)d_in[2];
  const float* Ws   = (const float*)d_in[3];
  const float* asrc = (const float*)d_in[4];
  const float* adst = (const float*)d_in[5];
  const float* bias = (const float*)d_in[6];
  const float* gam  = (const float*)d_in[7];
  const float* bet  = (const float*)d_in[8];
  const float* w1   = (const float*)d_in[9];
  const float* b1   = (const float*)d_in[10];
  const float* w2   = (const float*)d_in[11];
  const float* b2   = (const float*)d_in[12];
  float* out = (float*)d_out;

  char* wp = (char*)d_ws;
  auto carve = [&](size_t bytes) -> char* {
    char* p = wp;
    wp += (bytes + 255) & ~(size_t)255;
    return p;
  };
  float* A     = (float*)carve((size_t)NN * HIDD * 4);
  float* B     = (float*)carve((size_t)NN * HIDD * 4);
  float* esrc  = (float*)carve((size_t)NN * NHEAD * 4);
  float* edst  = (float*)carve((size_t)NN * NHEAD * 4);
  int* rowptr  = (int*)carve((size_t)(NN + 1) * 4);
  int* nxt     = (int*)carve((size_t)NN * 4);
  int* colb    = (int*)carve((size_t)EPTOT * 4);
  char* z0 = wp;
  int* deg     = (int*)carve((size_t)NN * 4);
  float* stats = (float*)carve(768 * 4);
  float* pooled= (float*)carve((size_t)GG * HIDD * 4);
  float* cnt   = (float*)carve((size_t)GG * 4);
  int zcount = (int)((wp - z0) / 4);

  zero_kernel<<<(zcount + 255) / 256, 256, 0, stream>>>((float*)z0, zcount);
  count_kernel<<<(EPTOT + 255) / 256, 256, 0, stream>>>(ei, deg);
  scan_kernel<<<1, 1024, 0, stream>>>(deg, rowptr, nxt);
  scatter_kernel<<<(EPTOT + 255) / 256, 256, 0, stream>>>(ei, nxt, colb);

  const float* xin = x;
  for (int l = 0; l < 3; ++l) {
    gemm_kernel<<<(NN + 31) / 32, 256, 0, stream>>>(xin, Ws + (size_t)l * HIDD * HIDD, A, NN);
    edot_kernel<<<(NN * NHEAD + 255) / 256, 256, 0, stream>>>(
        A, asrc + l * NHEAD * 32, adst + l * NHEAD * 32, esrc, edst);
    agg_kernel<<<(NN * 64 + 255) / 256, 256, 0, stream>>>(A, esrc, edst, rowptr, colb,
                                                          bias + l * HIDD, B);
    bnstat_kernel<<<256, 256, 0, stream>>>(B, stats + l * 256);
    bnapply_kernel<<<(NN * HIDD + 255) / 256, 256, 0, stream>>>(B, stats + l * 256,
                                                                gam + l * HIDD, bet + l * HIDD);
    xin = B;
  }
  pool_kernel<<<(NN * HIDD + 255) / 256, 256, 0, stream>>>(B, batch, pooled, cnt);
  head_kernel<<<(GG * 64 + 255) / 256, 256, 0, stream>>>(pooled, cnt, w1, b1, w2, b2, out);
}

// Round 2
// 698.834 us; speedup vs baseline: 1.2163x; 1.2163x over previous
//
#include <hip/hip_runtime.h>
#include <math.h>

#define NN 50000
#define EE 800000
#define GG 1024
#define HIDD 128
#define NHEAD 4
#define EPTOT (EE + NN)
#define NEG_SLOPE 0.2f
#define NB ((NN + 255) / 256)  // 196 blocks for scan

__global__ void zero_kernel(float* __restrict__ p, int n) {
  int i = blockIdx.x * blockDim.x + threadIdx.x;
  if (i < n) p[i] = 0.f;
}

__global__ void count_kernel(const int* __restrict__ ei, int* __restrict__ deg) {
  int e = blockIdx.x * blockDim.x + threadIdx.x;
  if (e >= EPTOT) return;
  int d = (e < EE) ? ei[EE + e] : (e - EE);
  atomicAdd(&deg[d], 1);
}

// stage A: per-block sums of deg (coalesced)
__global__ __launch_bounds__(256) void degsum_kernel(const int* __restrict__ deg,
                                                     int* __restrict__ bsum) {
  __shared__ int sh[256];
  int i = blockIdx.x * 256 + threadIdx.x;
  sh[threadIdx.x] = (i < NN) ? deg[i] : 0;
  __syncthreads();
  for (int off = 128; off > 0; off >>= 1) {
    if (threadIdx.x < off) sh[threadIdx.x] += sh[threadIdx.x + off];
    __syncthreads();
  }
  if (threadIdx.x == 0) bsum[blockIdx.x] = sh[0];
}

// stage B: scan the 196 block sums (one tiny block)
__global__ __launch_bounds__(256) void scanb_kernel(const int* __restrict__ bsum,
                                                    int* __restrict__ boff,
                                                    int* __restrict__ rowptr) {
  __shared__ int sh[256];
  int t = threadIdx.x;
  int v = (t < NB) ? bsum[t] : 0;
  sh[t] = v;
  __syncthreads();
  for (int off = 1; off < 256; off <<= 1) {
    int u = (t >= off) ? sh[t - off] : 0;
    __syncthreads();
    sh[t] += u;
    __syncthreads();
  }
  if (t < NB) boff[t] = sh[t] - v;  // exclusive block offset
  if (t == 255) rowptr[NN] = sh[255];
}

// stage C: per-block exclusive scan + block offset -> rowptr, nxt
__global__ __launch_bounds__(256) void rowptr_kernel(const int* __restrict__ deg,
                                                     const int* __restrict__ boff,
                                                     int* __restrict__ rowptr,
                                                     int* __restrict__ nxt) {
  __shared__ int sh[256];
  int t = threadIdx.x;
  int i = blockIdx.x * 256 + t;
  int v = (i < NN) ? deg[i] : 0;
  sh[t] = v;
  __syncthreads();
  for (int off = 1; off < 256; off <<= 1) {
    int u = (t >= off) ? sh[t - off] : 0;
    __syncthreads();
    sh[t] += u;
    __syncthreads();
  }
  if (i < NN) {
    int ex = boff[blockIdx.x] + sh[t] - v;
    rowptr[i] = ex;
    nxt[i] = ex;
  }
}

__global__ void scatter_kernel(const int* __restrict__ ei, int* __restrict__ nxt,
                               int* __restrict__ colb) {
  int e = blockIdx.x * blockDim.x + threadIdx.x;
  if (e >= EPTOT) return;
  int s, d;
  if (e < EE) { s = ei[e]; d = ei[EE + e]; } else { s = e - EE; d = s; }
  int pos = atomicAdd(&nxt[d], 1);
  colb[pos] = s;
}

__device__ inline void fma4(float4& a, float s, const float4& b) {
  a.x += s * b.x; a.y += s * b.y; a.z += s * b.z; a.w += s * b.w;
}

// C = X[rows x 128] @ W[128 x 128], 32 rows per block, thread tile 4x4
__global__ __launch_bounds__(256) void gemm_kernel(const float* __restrict__ X,
                                                   const float* __restrict__ Wm,
                                                   float* __restrict__ Y, int nrows) {
  __shared__ float wsh[HIDD][HIDD];
  __shared__ float xsh[32][HIDD];
  int tid = threadIdx.x;
  float* wflat = &wsh[0][0];
  for (int i = tid * 4; i < HIDD * HIDD; i += 1024)
    *(float4*)(wflat + i) = *(const float4*)(Wm + i);
  int row0 = blockIdx.x * 32;
  float* xflat = &xsh[0][0];
  for (int i = tid * 4; i < 32 * HIDD; i += 1024) {
    int r = i >> 7, c = i & 127;
    float4 v = make_float4(0.f, 0.f, 0.f, 0.f);
    if (row0 + r < nrows) v = *(const float4*)(X + (size_t)(row0 + r) * HIDD + c);
    *(float4*)(xflat + i) = v;
  }
  __syncthreads();
  int rg = tid >> 5;
  int cg = tid & 31;
  float4 acc[4];
#pragma unroll
  for (int i = 0; i < 4; ++i) acc[i] = make_float4(0.f, 0.f, 0.f, 0.f);
  for (int k = 0; k < HIDD; k += 4) {
    float4 wv[4];
#pragma unroll
    for (int j = 0; j < 4; ++j) wv[j] = *(float4*)&wsh[k + j][cg * 4];
#pragma unroll
    for (int i = 0; i < 4; ++i) {
      float4 xv = *(float4*)&xsh[rg * 4 + i][k];
      fma4(acc[i], xv.x, wv[0]);
      fma4(acc[i], xv.y, wv[1]);
      fma4(acc[i], xv.z, wv[2]);
      fma4(acc[i], xv.w, wv[3]);
    }
  }
#pragma unroll
  for (int i = 0; i < 4; ++i) {
    int r = row0 + rg * 4 + i;
    if (r < nrows) *(float4*)(Y + (size_t)r * HIDD + cg * 4) = acc[i];
  }
}

__global__ void edot_kernel(const float* __restrict__ Hm, const float* __restrict__ asrc,
                            const float* __restrict__ adst, float* __restrict__ esrc,
                            float* __restrict__ edst) {
  int gid = blockIdx.x * blockDim.x + threadIdx.x;
  if (gid >= NN * NHEAD) return;
  int node = gid >> 2, hd = gid & 3;
  const float* hp = Hm + (size_t)node * HIDD + hd * 32;
  const float* ap = asrc + hd * 32;
  const float* bp = adst + hd * 32;
  float s1 = 0.f, s2 = 0.f;
#pragma unroll
  for (int c = 0; c < 32; c += 4) {
    float4 hv = *(const float4*)(hp + c);
    float4 av = *(const float4*)(ap + c);
    float4 bv = *(const float4*)(bp + c);
    s1 += hv.x * av.x + hv.y * av.y + hv.z * av.z + hv.w * av.w;
    s2 += hv.x * bv.x + hv.y * bv.y + hv.z * bv.z + hv.w * bv.w;
  }
  esrc[gid] = s1;
  edst[gid] = s2;
}

// one 64-lane wave per dst node; lane owns channels 2l,2l+1 (head = l>>4)
__global__ __launch_bounds__(256) void agg_kernel(const float* __restrict__ Hm,
                                                  const float* __restrict__ esrc,
                                                  const float* __restrict__ edst,
                                                  const int* __restrict__ rowptr,
                                                  const int* __restrict__ colb,
                                                  const float* __restrict__ bias,
                                                  float* __restrict__ out) {
  int wid = (blockIdx.x * 256 + threadIdx.x) >> 6;
  int lane = threadIdx.x & 63;
  if (wid >= NN) return;
  int hd = lane >> 4;
  float ed = edst[wid * 4 + hd];
  int e0 = rowptr[wid], e1 = rowptr[wid + 1];
  float m = -1e30f, den = 0.f, ax = 0.f, ay = 0.f;
  const float* hbase = Hm + 2 * lane;
  for (int e = e0; e < e1; ++e) {
    int src = colb[e];
    float es = esrc[src * 4 + hd];
    float z = es + ed;
    z = (z > 0.f) ? z : NEG_SLOPE * z;
    float nm = fmaxf(m, z);
    float corr = __expf(m - nm);
    float p = __expf(z - nm);
    float2 hv = *(const float2*)(hbase + (size_t)src * HIDD);
    den = den * corr + p;
    ax = ax * corr + p * hv.x;
    ay = ay * corr + p * hv.y;
    m = nm;
  }
  float inv = 1.f / (den + 1e-16f);
  int c = 2 * lane;
  out[(size_t)wid * HIDD + c] = ax * inv + bias[c];
  out[(size_t)wid * HIDD + c + 1] = ay * inv + bias[c + 1];
}

__global__ __launch_bounds__(256) void bnstat_kernel(const float* __restrict__ X,
                                                     float* __restrict__ stat) {
  __shared__ float sh[256];
  int tid = threadIdx.x;
  int c = tid & 127;
  int half = tid >> 7;
  float s = 0.f, q = 0.f;
  for (int r = blockIdx.x * 2 + half; r < NN; r += gridDim.x * 2) {
    float v = X[(size_t)r * HIDD + c];
    s += v;
    q += v * v;
  }
  sh[tid] = s;
  __syncthreads();
  if (tid < 128) atomicAdd(&stat[c], s + sh[tid + 128]);
  __syncthreads();
  sh[tid] = q;
  __syncthreads();
  if (tid < 128) atomicAdd(&stat[128 + c], q + sh[tid + 128]);
}

__global__ void bnapply_kernel(float* __restrict__ X, const float* __restrict__ stat,
                               const float* __restrict__ gamma,
                               const float* __restrict__ beta) {
  int i = blockIdx.x * blockDim.x + threadIdx.x;
  if (i >= NN * HIDD) return;
  int c = i & 127;
  const float invN = 1.f / (float)NN;
  float mean = stat[c] * invN;
  float var = stat[128 + c] * invN - mean * mean;
  float scale = gamma[c] * rsqrtf(var + 1e-5f);
  float shift = beta[c] - mean * scale;
  float v = X[i] * scale + shift;
  X[i] = (v > 0.f) ? v : expm1f(v);
}

// graph boundaries from sorted batch
__global__ void gbound_kernel(const int* __restrict__ batch, int* __restrict__ gstart) {
  int i = blockIdx.x * blockDim.x + threadIdx.x;
  if (i >= NN) return;
  int cur = batch[i];
  int prev = (i == 0) ? -1 : batch[i - 1];
  for (int g = prev + 1; g <= cur; ++g) gstart[g] = i;
  if (i == NN - 1) {
    for (int g = cur + 1; g <= GG; ++g) gstart[g] = NN;
  }
}

// block per graph, thread per channel: segmented mean, no atomics
__global__ __launch_bounds__(128) void pool_kernel(const float* __restrict__ X,
                                                   const int* __restrict__ gstart,
                                                   float* __restrict__ pooled) {
  int g = blockIdx.x;
  int c = threadIdx.x;
  int n0 = gstart[g], n1 = gstart[g + 1];
  float s = 0.f;
  for (int n = n0; n < n1; ++n) s += X[(size_t)n * HIDD + c];
  float inv = (n1 > n0) ? 1.f / (float)(n1 - n0) : 0.f;
  pooled[(size_t)g * HIDD + c] = s * inv;
}

__global__ __launch_bounds__(256) void head_kernel(const float* __restrict__ pooled,
                                                   const float* __restrict__ w1,
                                                   const float* __restrict__ b1,
                                                   const float* __restrict__ w2,
                                                   const float* __restrict__ b2,
                                                   float* __restrict__ out) {
  int wid = (blockIdx.x * 256 + threadIdx.x) >> 6;
  int lane = threadIdx.x & 63;
  if (wid >= GG) return;
  float acc = b1[lane];
  const float* pg = pooled + (size_t)wid * HIDD;
  for (int k = 0; k < HIDD; ++k) {
    acc += pg[k] * w1[k * 64 + lane];
  }
  acc = fmaxf(acc, 0.f);
  float v = acc * w2[lane];
#pragma unroll
  for (int off = 32; off > 0; off >>= 1) v += __shfl_down(v, off);
  if (lane == 0) out[wid] = v + b2[0];
}

extern "C" void kernel_launch(void* const* d_in, const int* in_sizes, int n_in,
                              void* d_out, int out_size, void* d_ws, size_t ws_size,
                              hipStream_t stream) {
  const float* x    = (const float*)d_in[0];
  const int* ei     = (const int*)d_in[1];
  const int* batch  = (const int*)d_in[2];
  const float* Ws   = (const float*)d_in[3];
  const float* asrc = (const float*)d_in[4];
  const float* adst = (const float*)d_in[5];
  const float* bias = (const float*)d_in[6];
  const float* gam  = (const float*)d_in[7];
  const float* bet  = (const float*)d_in[8];
  const float* w1   = (const float*)d_in[9];
  const float* b1   = (const float*)d_in[10];
  const float* w2   = (const float*)d_in[11];
  const float* b2   = (const float*)d_in[12];
  float* out = (float*)d_out;

  char* wp = (char*)d_ws;
  auto carve = [&](size_t bytes) -> char* {
    char* p = wp;
    wp += (bytes + 255) & ~(size_t)255;
    return p;
  };
  float* A      = (float*)carve((size_t)NN * HIDD * 4);
  float* B      = (float*)carve((size_t)NN * HIDD * 4);
  float* esrc   = (float*)carve((size_t)NN * NHEAD * 4);
  float* edst   = (float*)carve((size_t)NN * NHEAD * 4);
  int* rowptr   = (int*)carve((size_t)(NN + 1) * 4);
  int* nxt      = (int*)carve((size_t)NN * 4);
  int* colb     = (int*)carve((size_t)EPTOT * 4);
  int* bsum     = (int*)carve((size_t)NB * 4);
  int* boff     = (int*)carve((size_t)NB * 4);
  int* gstart   = (int*)carve((size_t)(GG + 1) * 4);
  float* pooled = (float*)carve((size_t)GG * HIDD * 4);
  char* z0 = wp;
  int* deg      = (int*)carve((size_t)NN * 4);
  float* stats  = (float*)carve(768 * 4);
  int zcount = (int)((wp - z0) / 4);

  zero_kernel<<<(zcount + 255) / 256, 256, 0, stream>>>((float*)z0, zcount);
  count_kernel<<<(EPTOT + 255) / 256, 256, 0, stream>>>(ei, deg);
  degsum_kernel<<<NB, 256, 0, stream>>>(deg, bsum);
  scanb_kernel<<<1, 256, 0, stream>>>(bsum, boff, rowptr);
  rowptr_kernel<<<NB, 256, 0, stream>>>(deg, boff, rowptr, nxt);
  scatter_kernel<<<(EPTOT + 255) / 256, 256, 0, stream>>>(ei, nxt, colb);
  gbound_kernel<<<(NN + 255) / 256, 256, 0, stream>>>(batch, gstart);

  const float* xin = x;
  for (int l = 0; l < 3; ++l) {
    gemm_kernel<<<(NN + 31) / 32, 256, 0, stream>>>(xin, Ws + (size_t)l * HIDD * HIDD, A, NN);
    edot_kernel<<<(NN * NHEAD + 255) / 256, 256, 0, stream>>>(
        A, asrc + l * NHEAD * 32, adst + l * NHEAD * 32, esrc, edst);
    agg_kernel<<<(NN * 64 + 255) / 256, 256, 0, stream>>>(A, esrc, edst, rowptr, colb,
                                                          bias + l * HIDD, B);
    bnstat_kernel<<<256, 256, 0, stream>>>(B, stats + l * 256);
    bnapply_kernel<<<(NN * HIDD + 255) / 256, 256, 0, stream>>>(B, stats + l * 256,
                                                                gam + l * HIDD, bet + l * HIDD);
    xin = B;
  }
  pool_kernel<<<GG, 128, 0, stream>>>(B, gstart, pooled);
  head_kernel<<<(GG * 64 + 255) / 256, 256, 0, stream>>>(pooled, w1, b1, w2, b2, out);
}

// Round 3
// 554.437 us; speedup vs baseline: 1.5331x; 1.2604x over previous
//
#include <hip/hip_runtime.h>
#include <hip/hip_fp16.h>
#include <math.h>

#define NN 50000
#define EE 800000
#define GG 1024
#define HIDD 128
#define NHEAD 4
#define EPTOT (EE + NN)
#define NEG_SLOPE 0.2f
#define NB ((NN + 255) / 256)

__global__ void zero_kernel(float* __restrict__ p, int n) {
  int i = blockIdx.x * blockDim.x + threadIdx.x;
  if (i < n) p[i] = 0.f;
}

__global__ void count_kernel(const int* __restrict__ ei, int* __restrict__ deg) {
  int e = blockIdx.x * blockDim.x + threadIdx.x;
  if (e >= EPTOT) return;
  int d = (e < EE) ? ei[EE + e] : (e - EE);
  atomicAdd(&deg[d], 1);
}

__global__ __launch_bounds__(256) void degsum_kernel(const int* __restrict__ deg,
                                                     int* __restrict__ bsum) {
  __shared__ int sh[256];
  int i = blockIdx.x * 256 + threadIdx.x;
  sh[threadIdx.x] = (i < NN) ? deg[i] : 0;
  __syncthreads();
  for (int off = 128; off > 0; off >>= 1) {
    if (threadIdx.x < off) sh[threadIdx.x] += sh[threadIdx.x + off];
    __syncthreads();
  }
  if (threadIdx.x == 0) bsum[blockIdx.x] = sh[0];
}

__global__ __launch_bounds__(256) void scanb_kernel(const int* __restrict__ bsum,
                                                    int* __restrict__ boff,
                                                    int* __restrict__ rowptr) {
  __shared__ int sh[256];
  int t = threadIdx.x;
  int v = (t < NB) ? bsum[t] : 0;
  sh[t] = v;
  __syncthreads();
  for (int off = 1; off < 256; off <<= 1) {
    int u = (t >= off) ? sh[t - off] : 0;
    __syncthreads();
    sh[t] += u;
    __syncthreads();
  }
  if (t < NB) boff[t] = sh[t] - v;
  if (t == 255) rowptr[NN] = sh[255];
}

__global__ __launch_bounds__(256) void rowptr_kernel(const int* __restrict__ deg,
                                                     const int* __restrict__ boff,
                                                     int* __restrict__ rowptr,
                                                     int* __restrict__ nxt) {
  __shared__ int sh[256];
  int t = threadIdx.x;
  int i = blockIdx.x * 256 + t;
  int v = (i < NN) ? deg[i] : 0;
  sh[t] = v;
  __syncthreads();
  for (int off = 1; off < 256; off <<= 1) {
    int u = (t >= off) ? sh[t - off] : 0;
    __syncthreads();
    sh[t] += u;
    __syncthreads();
  }
  if (i < NN) {
    int ex = boff[blockIdx.x] + sh[t] - v;
    rowptr[i] = ex;
    nxt[i] = ex;
  }
}

__global__ void scatter_kernel(const int* __restrict__ ei, int* __restrict__ nxt,
                               int* __restrict__ colb) {
  int e = blockIdx.x * blockDim.x + threadIdx.x;
  if (e >= EPTOT) return;
  int s, d;
  if (e < EE) { s = ei[e]; d = ei[EE + e]; } else { s = e - EE; d = s; }
  int pos = atomicAdd(&nxt[d], 1);
  colb[pos] = s;
}

__device__ inline void fma4(float4& a, float s, const float4& b) {
  a.x += s * b.x; a.y += s * b.y; a.z += s * b.z; a.w += s * b.w;
}

__device__ inline float bnelu1(float v, float scale, float shift) {
  v = v * scale + shift;
  return (v > 0.f) ? v : expm1f(v);
}

// GEMM 32 rows/block + fused: BN+ELU on input staging (stat!=null),
// f16 output write, e_src/e_dst epilogue (replaces edot).
__global__ __launch_bounds__(256) void gemm_kernel(
    const float* __restrict__ X, const float* __restrict__ Wm,
    const float* __restrict__ stat, const float* __restrict__ gamma,
    const float* __restrict__ beta, const float* __restrict__ asrc,
    const float* __restrict__ adst, __half* __restrict__ Hh,
    float* __restrict__ esrc, float* __restrict__ edst, int nrows) {
  __shared__ float wsh[HIDD][HIDD];
  __shared__ float xsh[32][HIDD];
  int tid = threadIdx.x;
  float* wflat = &wsh[0][0];
  for (int i = tid * 4; i < HIDD * HIDD; i += 1024)
    *(float4*)(wflat + i) = *(const float4*)(Wm + i);
  int row0 = blockIdx.x * 32;
  float* xflat = &xsh[0][0];
  const float invN = 1.f / (float)NN;
  for (int i = tid * 4; i < 32 * HIDD; i += 1024) {
    int r = i >> 7, c = i & 127;
    float4 v = make_float4(0.f, 0.f, 0.f, 0.f);
    if (row0 + r < nrows) {
      v = *(const float4*)(X + (size_t)(row0 + r) * HIDD + c);
      if (stat) {
#pragma unroll
        for (int j = 0; j < 4; ++j) {
          float mean = stat[c + j] * invN;
          float var = stat[128 + c + j] * invN - mean * mean;
          float scale = gamma[c + j] * rsqrtf(var + 1e-5f);
          float shift = beta[c + j] - mean * scale;
          ((float*)&v)[j] = bnelu1(((float*)&v)[j], scale, shift);
        }
      }
    }
    *(float4*)(xflat + i) = v;
  }
  __syncthreads();
  int rg = tid >> 5;
  int cg = tid & 31;
  float4 acc[4];
#pragma unroll
  for (int i = 0; i < 4; ++i) acc[i] = make_float4(0.f, 0.f, 0.f, 0.f);
  for (int k = 0; k < HIDD; k += 4) {
    float4 wv[4];
#pragma unroll
    for (int j = 0; j < 4; ++j) wv[j] = *(float4*)&wsh[k + j][cg * 4];
#pragma unroll
    for (int i = 0; i < 4; ++i) {
      float4 xv = *(float4*)&xsh[rg * 4 + i][k];
      fma4(acc[i], xv.x, wv[0]);
      fma4(acc[i], xv.y, wv[1]);
      fma4(acc[i], xv.z, wv[2]);
      fma4(acc[i], xv.w, wv[3]);
    }
  }
  // epilogue: f16 store + per-head attention-logit partial dots
  int hd = cg >> 3;
  float4 av = *(const float4*)(asrc + cg * 4);
  float4 bv = *(const float4*)(adst + cg * 4);
  float ps[4], pd[4];
#pragma unroll
  for (int i = 0; i < 4; ++i) {
    ps[i] = acc[i].x * av.x + acc[i].y * av.y + acc[i].z * av.z + acc[i].w * av.w;
    pd[i] = acc[i].x * bv.x + acc[i].y * bv.y + acc[i].z * bv.z + acc[i].w * bv.w;
  }
#pragma unroll
  for (int off = 4; off > 0; off >>= 1) {
#pragma unroll
    for (int i = 0; i < 4; ++i) {
      ps[i] += __shfl_down(ps[i], off);
      pd[i] += __shfl_down(pd[i], off);
    }
  }
#pragma unroll
  for (int i = 0; i < 4; ++i) {
    int r = row0 + rg * 4 + i;
    if (r < nrows) {
      __half2* hp = (__half2*)(Hh + (size_t)r * HIDD) + cg * 2;
      hp[0] = __floats2half2_rn(acc[i].x, acc[i].y);
      hp[1] = __floats2half2_rn(acc[i].z, acc[i].w);
      if ((cg & 7) == 0) {
        esrc[r * 4 + hd] = ps[i];
        edst[r * 4 + hd] = pd[i];
      }
    }
  }
}

// one wave per dst node; lane owns channels 2l,2l+1 (head = l>>4).
// logits are bounded (|z| << 80) so exp without max-subtraction is exact.
__global__ __launch_bounds__(256) void agg_kernel(const __half2* __restrict__ Hh,
                                                  const float* __restrict__ esrc,
                                                  const float* __restrict__ edst,
                                                  const int* __restrict__ rowptr,
                                                  const int* __restrict__ colb,
                                                  const float* __restrict__ bias,
                                                  float* __restrict__ out) {
  int wid = (blockIdx.x * 256 + threadIdx.x) >> 6;
  int lane = threadIdx.x & 63;
  if (wid >= NN) return;
  int hd = lane >> 4;
  float ed = edst[wid * 4 + hd];
  int e0 = rowptr[wid], e1 = rowptr[wid + 1];
  float den = 0.f, ax = 0.f, ay = 0.f;
  const __half2* hbase = Hh + lane;
#pragma unroll 2
  for (int e = e0; e < e1; ++e) {
    int src = colb[e];
    float es = esrc[src * 4 + hd];
    __half2 hv = hbase[(size_t)src * 64];
    float z = es + ed;
    z = (z > 0.f) ? z : NEG_SLOPE * z;
    float w = __expf(z);
    float2 f = __half22float2(hv);
    den += w;
    ax += w * f.x;
    ay += w * f.y;
  }
  float inv = 1.f / (den + 1e-16f);
  int c = 2 * lane;
  out[(size_t)wid * HIDD + c] = ax * inv + bias[c];
  out[(size_t)wid * HIDD + c + 1] = ay * inv + bias[c + 1];
}

__global__ __launch_bounds__(256) void bnstat_kernel(const float* __restrict__ X,
                                                     float* __restrict__ stat) {
  __shared__ float sh[256];
  int tid = threadIdx.x;
  int c = tid & 127;
  int half = tid >> 7;
  float s = 0.f, q = 0.f;
  for (int r = blockIdx.x * 2 + half; r < NN; r += gridDim.x * 2) {
    float v = X[(size_t)r * HIDD + c];
    s += v;
    q += v * v;
  }
  sh[tid] = s;
  __syncthreads();
  if (tid < 128) atomicAdd(&stat[c], s + sh[tid + 128]);
  __syncthreads();
  sh[tid] = q;
  __syncthreads();
  if (tid < 128) atomicAdd(&stat[128 + c], q + sh[tid + 128]);
}

__global__ void gbound_kernel(const int* __restrict__ batch, int* __restrict__ gstart) {
  int i = blockIdx.x * blockDim.x + threadIdx.x;
  if (i >= NN) return;
  int cur = batch[i];
  int prev = (i == 0) ? -1 : batch[i - 1];
  for (int g = prev + 1; g <= cur; ++g) gstart[g] = i;
  if (i == NN - 1) {
    for (int g = cur + 1; g <= GG; ++g) gstart[g] = NN;
  }
}

// block per graph, thread per channel; applies final BN+ELU inline
__global__ __launch_bounds__(128) void pool_kernel(const float* __restrict__ X,
                                                   const int* __restrict__ gstart,
                                                   const float* __restrict__ stat,
                                                   const float* __restrict__ gamma,
                                                   const float* __restrict__ beta,
                                                   float* __restrict__ pooled) {
  int g = blockIdx.x;
  int c = threadIdx.x;
  const float invN = 1.f / (float)NN;
  float mean = stat[c] * invN;
  float var = stat[128 + c] * invN - mean * mean;
  float scale = gamma[c] * rsqrtf(var + 1e-5f);
  float shift = beta[c] - mean * scale;
  int n0 = gstart[g], n1 = gstart[g + 1];
  float s = 0.f;
  for (int n = n0; n < n1; ++n) s += bnelu1(X[(size_t)n * HIDD + c], scale, shift);
  float inv = (n1 > n0) ? 1.f / (float)(n1 - n0) : 0.f;
  pooled[(size_t)g * HIDD + c] = s * inv;
}

__global__ __launch_bounds__(256) void head_kernel(const float* __restrict__ pooled,
                                                   const float* __restrict__ w1,
                                                   const float* __restrict__ b1,
                                                   const float* __restrict__ w2,
                                                   const float* __restrict__ b2,
                                                   float* __restrict__ out) {
  int wid = (blockIdx.x * 256 + threadIdx.x) >> 6;
  int lane = threadIdx.x & 63;
  if (wid >= GG) return;
  float acc = b1[lane];
  const float* pg = pooled + (size_t)wid * HIDD;
  for (int k = 0; k < HIDD; ++k) {
    acc += pg[k] * w1[k * 64 + lane];
  }
  acc = fmaxf(acc, 0.f);
  float v = acc * w2[lane];
#pragma unroll
  for (int off = 32; off > 0; off >>= 1) v += __shfl_down(v, off);
  if (lane == 0) out[wid] = v + b2[0];
}

extern "C" void kernel_launch(void* const* d_in, const int* in_sizes, int n_in,
                              void* d_out, int out_size, void* d_ws, size_t ws_size,
                              hipStream_t stream) {
  const float* x    = (const float*)d_in[0];
  const int* ei     = (const int*)d_in[1];
  const int* batch  = (const int*)d_in[2];
  const float* Ws   = (const float*)d_in[3];
  const float* asrc = (const float*)d_in[4];
  const float* adst = (const float*)d_in[5];
  const float* bias = (const float*)d_in[6];
  const float* gam  = (const float*)d_in[7];
  const float* bet  = (const float*)d_in[8];
  const float* w1   = (const float*)d_in[9];
  const float* b1   = (const float*)d_in[10];
  const float* w2   = (const float*)d_in[11];
  const float* b2   = (const float*)d_in[12];
  float* out = (float*)d_out;

  char* wp = (char*)d_ws;
  auto carve = [&](size_t bytes) -> char* {
    char* p = wp;
    wp += (bytes + 255) & ~(size_t)255;
    return p;
  };
  float* B      = (float*)carve((size_t)NN * HIDD * 4);
  __half* Hh    = (__half*)carve((size_t)NN * HIDD * 2);
  float* esrc   = (float*)carve((size_t)NN * NHEAD * 4);
  float* edst   = (float*)carve((size_t)NN * NHEAD * 4);
  int* rowptr   = (int*)carve((size_t)(NN + 1) * 4);
  int* nxt      = (int*)carve((size_t)NN * 4);
  int* colb     = (int*)carve((size_t)EPTOT * 4);
  int* bsum     = (int*)carve((size_t)NB * 4);
  int* boff     = (int*)carve((size_t)NB * 4);
  int* gstart   = (int*)carve((size_t)(GG + 1) * 4);
  float* pooled = (float*)carve((size_t)GG * HIDD * 4);
  char* z0 = wp;
  int* deg      = (int*)carve((size_t)NN * 4);
  float* stats  = (float*)carve(768 * 4);
  int zcount = (int)((wp - z0) / 4);

  zero_kernel<<<(zcount + 255) / 256, 256, 0, stream>>>((float*)z0, zcount);
  count_kernel<<<(EPTOT + 255) / 256, 256, 0, stream>>>(ei, deg);
  degsum_kernel<<<NB, 256, 0, stream>>>(deg, bsum);
  scanb_kernel<<<1, 256, 0, stream>>>(bsum, boff, rowptr);
  rowptr_kernel<<<NB, 256, 0, stream>>>(deg, boff, rowptr, nxt);
  scatter_kernel<<<(EPTOT + 255) / 256, 256, 0, stream>>>(ei, nxt, colb);
  gbound_kernel<<<(NN + 255) / 256, 256, 0, stream>>>(batch, gstart);

  const float* xin = x;
  for (int l = 0; l < 3; ++l) {
    const float* stat_prev = (l == 0) ? nullptr : stats + (l - 1) * 256;
    const float* gam_prev = (l == 0) ? nullptr : gam + (l - 1) * HIDD;
    const float* bet_prev = (l == 0) ? nullptr : bet + (l - 1) * HIDD;
    gemm_kernel<<<(NN + 31) / 32, 256, 0, stream>>>(
        xin, Ws + (size_t)l * HIDD * HIDD, stat_prev, gam_prev, bet_prev,
        asrc + l * NHEAD * 32, adst + l * NHEAD * 32, Hh, esrc, edst, NN);
    agg_kernel<<<(NN * 64 + 255) / 256, 256, 0, stream>>>(
        (const __half2*)Hh, esrc, edst, rowptr, colb, bias + l * HIDD, B);
    bnstat_kernel<<<256, 256, 0, stream>>>(B, stats + l * 256);
    xin = B;
  }
  pool_kernel<<<GG, 128, 0, stream>>>(B, gstart, stats + 2 * 256, gam + 2 * HIDD,
                                      bet + 2 * HIDD, pooled);
  head_kernel<<<(GG * 64 + 255) / 256, 256, 0, stream>>>(pooled, w1, b1, w2, b2, out);
}

// Round 4
// 474.263 us; speedup vs baseline: 1.7923x; 1.1690x over previous
//
#include <hip/hip_runtime.h>
#include <hip/hip_fp16.h>
#include <math.h>

#define NN 50000
#define EE 800000
#define GG 1024
#define HIDD 128
#define NHEAD 4
#define EPTOT (EE + NN)
#define NEG_SLOPE 0.2f
#define NB ((NN + 255) / 256)
#define NTILE (NN / 16)  // 3125 wave-tiles, exact

typedef _Float16 f16x8 __attribute__((ext_vector_type(8)));
typedef float f32x4 __attribute__((ext_vector_type(4)));

__global__ void zero_kernel(float* __restrict__ p, int n) {
  int i = blockIdx.x * blockDim.x + threadIdx.x;
  if (i < n) p[i] = 0.f;
}

__global__ void count_kernel(const int* __restrict__ ei, int* __restrict__ deg) {
  int e = blockIdx.x * blockDim.x + threadIdx.x;
  if (e >= EPTOT) return;
  int d = (e < EE) ? ei[EE + e] : (e - EE);
  atomicAdd(&deg[d], 1);
}

__global__ __launch_bounds__(256) void degsum_kernel(const int* __restrict__ deg,
                                                     int* __restrict__ bsum) {
  __shared__ int sh[256];
  int i = blockIdx.x * 256 + threadIdx.x;
  sh[threadIdx.x] = (i < NN) ? deg[i] : 0;
  __syncthreads();
  for (int off = 128; off > 0; off >>= 1) {
    if (threadIdx.x < off) sh[threadIdx.x] += sh[threadIdx.x + off];
    __syncthreads();
  }
  if (threadIdx.x == 0) bsum[blockIdx.x] = sh[0];
}

__global__ __launch_bounds__(256) void scanb_kernel(const int* __restrict__ bsum,
                                                    int* __restrict__ boff,
                                                    int* __restrict__ rowptr) {
  __shared__ int sh[256];
  int t = threadIdx.x;
  int v = (t < NB) ? bsum[t] : 0;
  sh[t] = v;
  __syncthreads();
  for (int off = 1; off < 256; off <<= 1) {
    int u = (t >= off) ? sh[t - off] : 0;
    __syncthreads();
    sh[t] += u;
    __syncthreads();
  }
  if (t < NB) boff[t] = sh[t] - v;
  if (t == 255) rowptr[NN] = sh[255];
}

__global__ __launch_bounds__(256) void rowptr_kernel(const int* __restrict__ deg,
                                                     const int* __restrict__ boff,
                                                     int* __restrict__ rowptr,
                                                     int* __restrict__ nxt) {
  __shared__ int sh[256];
  int t = threadIdx.x;
  int i = blockIdx.x * 256 + t;
  int v = (i < NN) ? deg[i] : 0;
  sh[t] = v;
  __syncthreads();
  for (int off = 1; off < 256; off <<= 1) {
    int u = (t >= off) ? sh[t - off] : 0;
    __syncthreads();
    sh[t] += u;
    __syncthreads();
  }
  if (i < NN) {
    int ex = boff[blockIdx.x] + sh[t] - v;
    rowptr[i] = ex;
    nxt[i] = ex;
  }
}

__global__ void scatter_kernel(const int* __restrict__ ei, int* __restrict__ nxt,
                               int* __restrict__ colb) {
  int e = blockIdx.x * blockDim.x + threadIdx.x;
  if (e >= EPTOT) return;
  int s, d;
  if (e < EE) { s = ei[e]; d = ei[EE + e]; } else { s = e - EE; d = s; }
  int pos = atomicAdd(&nxt[d], 1);
  colb[pos] = s;
}

__device__ inline float bnelu1(float v, float scale, float shift) {
  v = v * scale + shift;
  return (v > 0.f) ? v : expm1f(v);
}

// pack W[layer] (128x128 f32 row-major) into MFMA A-fragment order, f16.
// frag id r = (ctile*4 + ks)*64 + lane; element j: W[ks*32+(lane>>4)*8+j][ctile*16+(lane&15)]
__global__ __launch_bounds__(256) void prepack_kernel(const float* __restrict__ Ws,
                                                      _Float16* __restrict__ Wp) {
  int f = blockIdx.x * 256 + threadIdx.x;
  if (f >= 3 * 2048) return;
  int layer = f >> 11, r = f & 2047;
  int ctile = r >> 8, ks = (r >> 6) & 3, lane = r & 63;
  const float* W = Ws + (size_t)layer * HIDD * HIDD;
  int col = ctile * 16 + (lane & 15);
  int krow = ks * 32 + (lane >> 4) * 8;
  f16x8 v;
#pragma unroll
  for (int j = 0; j < 8; ++j) v[j] = (_Float16)W[(krow + j) * HIDD + col];
  *(f16x8*)(Wp + (size_t)f * 8) = v;
}

// scale/shift from batch stats (one 128-thread block)
__global__ void bnfinal_kernel(const float* __restrict__ stat,
                               const float* __restrict__ gamma,
                               const float* __restrict__ beta,
                               float* __restrict__ scsh) {
  int c = threadIdx.x;
  const float invN = 1.f / (float)NN;
  float mean = stat[c] * invN;
  float var = stat[128 + c] * invN - mean * mean;
  float scale = gamma[c] * rsqrtf(var + 1e-5f);
  scsh[c] = scale;
  scsh[128 + c] = beta[c] - mean * scale;
}

// MFMA GEMM, operand-swapped: D = W^T-frag x X^T-frag = Y^T tiles.
// wave computes 16 nodes x 128 channels; BN+ELU fused on input; f16 H out;
// e_src/e_dst epilogue. No LDS.
__global__ __launch_bounds__(256) void gemm_mfma_kernel(
    const float* __restrict__ X, const _Float16* __restrict__ Wp,
    const float* __restrict__ scsh, const float* __restrict__ asrc,
    const float* __restrict__ adst, __half* __restrict__ Hh,
    float* __restrict__ esrc, float* __restrict__ edst) {
  int wave = threadIdx.x >> 6, lane = threadIdx.x & 63;
  int jt = blockIdx.x * 4 + wave;
  if (jt >= NTILE) return;
  int nl = lane & 15, kg = lane >> 4;
  int node = jt * 16 + nl;
  const float* xrow = X + (size_t)node * HIDD;
  f32x4 acc[8];
#pragma unroll
  for (int c = 0; c < 8; ++c) acc[c] = (f32x4){0.f, 0.f, 0.f, 0.f};
#pragma unroll
  for (int ks = 0; ks < 4; ++ks) {
    int k0 = ks * 32 + kg * 8;
    float4 va = *(const float4*)(xrow + k0);
    float4 vb = *(const float4*)(xrow + k0 + 4);
    if (scsh) {
      float4 s0 = *(const float4*)(scsh + k0);
      float4 s1 = *(const float4*)(scsh + k0 + 4);
      float4 t0 = *(const float4*)(scsh + HIDD + k0);
      float4 t1 = *(const float4*)(scsh + HIDD + k0 + 4);
      va.x = bnelu1(va.x, s0.x, t0.x); va.y = bnelu1(va.y, s0.y, t0.y);
      va.z = bnelu1(va.z, s0.z, t0.z); va.w = bnelu1(va.w, s0.w, t0.w);
      vb.x = bnelu1(vb.x, s1.x, t1.x); vb.y = bnelu1(vb.y, s1.y, t1.y);
      vb.z = bnelu1(vb.z, s1.z, t1.z); vb.w = bnelu1(vb.w, s1.w, t1.w);
    }
    f16x8 bfrag;
    bfrag[0] = (_Float16)va.x; bfrag[1] = (_Float16)va.y;
    bfrag[2] = (_Float16)va.z; bfrag[3] = (_Float16)va.w;
    bfrag[4] = (_Float16)vb.x; bfrag[5] = (_Float16)vb.y;
    bfrag[6] = (_Float16)vb.z; bfrag[7] = (_Float16)vb.w;
#pragma unroll
    for (int c = 0; c < 8; ++c) {
      f16x8 afrag = *(const f16x8*)(Wp + (((size_t)(c * 4 + ks) * 64 + lane) << 3));
      acc[c] = __builtin_amdgcn_mfma_f32_16x16x32_f16(afrag, bfrag, acc[c], 0, 0, 0);
    }
  }
  // epilogue: lane holds channels c*16 + kg*4 + {0..3} of `node`
  float es_p[4] = {0.f, 0.f, 0.f, 0.f};
  float ed_p[4] = {0.f, 0.f, 0.f, 0.f};
  __half* hrow = Hh + (size_t)node * HIDD;
#pragma unroll
  for (int c = 0; c < 8; ++c) {
    int ch0 = c * 16 + kg * 4;
    __half2 h01 = __floats2half2_rn(acc[c][0], acc[c][1]);
    __half2 h23 = __floats2half2_rn(acc[c][2], acc[c][3]);
    union { __half2 h[2]; float2 f; } u;
    u.h[0] = h01; u.h[1] = h23;
    *(float2*)(hrow + ch0) = u.f;
    float4 av = *(const float4*)(asrc + ch0);
    float4 bv = *(const float4*)(adst + ch0);
    int hd = c >> 1;
    es_p[hd] += acc[c][0] * av.x + acc[c][1] * av.y + acc[c][2] * av.z + acc[c][3] * av.w;
    ed_p[hd] += acc[c][0] * bv.x + acc[c][1] * bv.y + acc[c][2] * bv.z + acc[c][3] * bv.w;
  }
#pragma unroll
  for (int hd = 0; hd < 4; ++hd) {
    es_p[hd] += __shfl_xor(es_p[hd], 16);
    es_p[hd] += __shfl_xor(es_p[hd], 32);
    ed_p[hd] += __shfl_xor(ed_p[hd], 16);
    ed_p[hd] += __shfl_xor(ed_p[hd], 32);
  }
  float es_o = (kg == 0) ? es_p[0] : (kg == 1) ? es_p[1] : (kg == 2) ? es_p[2] : es_p[3];
  float ed_o = (kg == 0) ? ed_p[0] : (kg == 1) ? ed_p[1] : (kg == 2) ? ed_p[2] : ed_p[3];
  esrc[node * 4 + kg] = es_o;
  edst[node * 4 + kg] = ed_o;
}

// one wave per dst node; lane owns channels 2l,2l+1 (head = l>>4)
__global__ __launch_bounds__(256) void agg_kernel(const __half2* __restrict__ Hh,
                                                  const float* __restrict__ esrc,
                                                  const float* __restrict__ edst,
                                                  const int* __restrict__ rowptr,
                                                  const int* __restrict__ colb,
                                                  const float* __restrict__ bias,
                                                  float* __restrict__ out) {
  int wid = (blockIdx.x * 256 + threadIdx.x) >> 6;
  int lane = threadIdx.x & 63;
  if (wid >= NN) return;
  int hd = lane >> 4;
  float ed = edst[wid * 4 + hd];
  int e0 = rowptr[wid], e1 = rowptr[wid + 1];
  float den = 0.f, ax = 0.f, ay = 0.f;
  const __half2* hbase = Hh + lane;
#pragma unroll 2
  for (int e = e0; e < e1; ++e) {
    int src = colb[e];
    float es = esrc[src * 4 + hd];
    __half2 hv = hbase[(size_t)src * 64];
    float z = es + ed;
    z = (z > 0.f) ? z : NEG_SLOPE * z;
    float w = __expf(z);
    float2 f = __half22float2(hv);
    den += w;
    ax += w * f.x;
    ay += w * f.y;
  }
  float inv = 1.f / (den + 1e-16f);
  int c = 2 * lane;
  out[(size_t)wid * HIDD + c] = ax * inv + bias[c];
  out[(size_t)wid * HIDD + c + 1] = ay * inv + bias[c + 1];
}

__global__ __launch_bounds__(256) void bnstat_kernel(const float* __restrict__ X,
                                                     float* __restrict__ stat) {
  __shared__ float sh[256];
  int tid = threadIdx.x;
  int c = tid & 127;
  int half = tid >> 7;
  float s = 0.f, q = 0.f;
  for (int r = blockIdx.x * 2 + half; r < NN; r += gridDim.x * 2) {
    float v = X[(size_t)r * HIDD + c];
    s += v;
    q += v * v;
  }
  sh[tid] = s;
  __syncthreads();
  if (tid < 128) atomicAdd(&stat[c], s + sh[tid + 128]);
  __syncthreads();
  sh[tid] = q;
  __syncthreads();
  if (tid < 128) atomicAdd(&stat[128 + c], q + sh[tid + 128]);
}

__global__ void gbound_kernel(const int* __restrict__ batch, int* __restrict__ gstart) {
  int i = blockIdx.x * blockDim.x + threadIdx.x;
  if (i >= NN) return;
  int cur = batch[i];
  int prev = (i == 0) ? -1 : batch[i - 1];
  for (int g = prev + 1; g <= cur; ++g) gstart[g] = i;
  if (i == NN - 1) {
    for (int g = cur + 1; g <= GG; ++g) gstart[g] = NN;
  }
}

// block per graph, thread per channel; applies final BN+ELU via scsh
__global__ __launch_bounds__(128) void pool_kernel(const float* __restrict__ X,
                                                   const int* __restrict__ gstart,
                                                   const float* __restrict__ scsh,
                                                   float* __restrict__ pooled) {
  int g = blockIdx.x;
  int c = threadIdx.x;
  float scale = scsh[c];
  float shift = scsh[128 + c];
  int n0 = gstart[g], n1 = gstart[g + 1];
  float s = 0.f;
  for (int n = n0; n < n1; ++n) s += bnelu1(X[(size_t)n * HIDD + c], scale, shift);
  float inv = (n1 > n0) ? 1.f / (float)(n1 - n0) : 0.f;
  pooled[(size_t)g * HIDD + c] = s * inv;
}

__global__ __launch_bounds__(256) void head_kernel(const float* __restrict__ pooled,
                                                   const float* __restrict__ w1,
                                                   const float* __restrict__ b1,
                                                   const float* __restrict__ w2,
                                                   const float* __restrict__ b2,
                                                   float* __restrict__ out) {
  int wid = (blockIdx.x * 256 + threadIdx.x) >> 6;
  int lane = threadIdx.x & 63;
  if (wid >= GG) return;
  float acc = b1[lane];
  const float* pg = pooled + (size_t)wid * HIDD;
  for (int k = 0; k < HIDD; ++k) {
    acc += pg[k] * w1[k * 64 + lane];
  }
  acc = fmaxf(acc, 0.f);
  float v = acc * w2[lane];
#pragma unroll
  for (int off = 32; off > 0; off >>= 1) v += __shfl_down(v, off);
  if (lane == 0) out[wid] = v + b2[0];
}

extern "C" void kernel_launch(void* const* d_in, const int* in_sizes, int n_in,
                              void* d_out, int out_size, void* d_ws, size_t ws_size,
                              hipStream_t stream) {
  const float* x    = (const float*)d_in[0];
  const int* ei     = (const int*)d_in[1];
  const int* batch  = (const int*)d_in[2];
  const float* Ws   = (const float*)d_in[3];
  const float* asrc = (const float*)d_in[4];
  const float* adst = (const float*)d_in[5];
  const float* bias = (const float*)d_in[6];
  const float* gam  = (const float*)d_in[7];
  const float* bet  = (const float*)d_in[8];
  const float* w1   = (const float*)d_in[9];
  const float* b1   = (const float*)d_in[10];
  const float* w2   = (const float*)d_in[11];
  const float* b2   = (const float*)d_in[12];
  float* out = (float*)d_out;

  char* wp = (char*)d_ws;
  auto carve = [&](size_t bytes) -> char* {
    char* p = wp;
    wp += (bytes + 255) & ~(size_t)255;
    return p;
  };
  float* B      = (float*)carve((size_t)NN * HIDD * 4);
  __half* Hh    = (__half*)carve((size_t)NN * HIDD * 2);
  _Float16* Wp  = (_Float16*)carve((size_t)3 * HIDD * HIDD * 2);
  float* scsh   = (float*)carve((size_t)3 * 256 * 4);
  float* esrc   = (float*)carve((size_t)NN * NHEAD * 4);
  float* edst   = (float*)carve((size_t)NN * NHEAD * 4);
  int* rowptr   = (int*)carve((size_t)(NN + 1) * 4);
  int* nxt      = (int*)carve((size_t)NN * 4);
  int* colb     = (int*)carve((size_t)EPTOT * 4);
  int* bsum     = (int*)carve((size_t)NB * 4);
  int* boff     = (int*)carve((size_t)NB * 4);
  int* gstart   = (int*)carve((size_t)(GG + 1) * 4);
  float* pooled = (float*)carve((size_t)GG * HIDD * 4);
  char* z0 = wp;
  int* deg      = (int*)carve((size_t)NN * 4);
  float* stats  = (float*)carve(768 * 4);
  int zcount = (int)((wp - z0) / 4);

  zero_kernel<<<(zcount + 255) / 256, 256, 0, stream>>>((float*)z0, zcount);
  prepack_kernel<<<24, 256, 0, stream>>>(Ws, Wp);
  count_kernel<<<(EPTOT + 255) / 256, 256, 0, stream>>>(ei, deg);
  degsum_kernel<<<NB, 256, 0, stream>>>(deg, bsum);
  scanb_kernel<<<1, 256, 0, stream>>>(bsum, boff, rowptr);
  rowptr_kernel<<<NB, 256, 0, stream>>>(deg, boff, rowptr, nxt);
  scatter_kernel<<<(EPTOT + 255) / 256, 256, 0, stream>>>(ei, nxt, colb);
  gbound_kernel<<<(NN + 255) / 256, 256, 0, stream>>>(batch, gstart);

  const float* xin = x;
  for (int l = 0; l < 3; ++l) {
    const float* sc_prev = (l == 0) ? nullptr : scsh + (l - 1) * 256;
    gemm_mfma_kernel<<<(NTILE + 3) / 4, 256, 0, stream>>>(
        xin, Wp + (size_t)l * HIDD * HIDD, sc_prev,
        asrc + l * NHEAD * 32, adst + l * NHEAD * 32, Hh, esrc, edst);
    agg_kernel<<<(NN * 64 + 255) / 256, 256, 0, stream>>>(
        (const __half2*)Hh, esrc, edst, rowptr, colb, bias + l * HIDD, B);
    bnstat_kernel<<<256, 256, 0, stream>>>(B, stats + l * 256);
    bnfinal_kernel<<<1, 128, 0, stream>>>(stats + l * 256, gam + l * HIDD,
                                          bet + l * HIDD, scsh + l * 256);
    xin = B;
  }
  pool_kernel<<<GG, 128, 0, stream>>>(B, gstart, scsh + 2 * 256, pooled);
  head_kernel<<<(GG * 64 + 255) / 256, 256, 0, stream>>>(pooled, w1, b1, w2, b2, out);
}

// Round 5
// 450.454 us; speedup vs baseline: 1.8870x; 1.0529x over previous
//
#include <hip/hip_runtime.h>
#include <hip/hip_fp16.h>
#include <math.h>

#define NN 50000
#define EE 800000
#define GG 1024
#define HIDD 128
#define NHEAD 4
#define EPTOT (EE + NN)
#define NEG_SLOPE 0.2f
#define NB ((NN + 255) / 256)
#define NTILE (NN / 16)  // 3125 wave-tiles, exact

#define BSHIFT 9          // 512 nodes per bucket
#define NBUK 98           // ceil(50000/512)
#define PCHUNK 4096       // edges per partition block
#define BCAP 10240        // staged colb entries per bucket (mean 8674, +5 sigma ~9140)

typedef _Float16 f16x8 __attribute__((ext_vector_type(8)));
typedef float f32x4 __attribute__((ext_vector_type(4)));

__global__ void zero_kernel(float* __restrict__ p, int n) {
  int i = blockIdx.x * blockDim.x + threadIdx.x;
  if (i < n) p[i] = 0.f;
}

__global__ void count_kernel(const int* __restrict__ ei, int* __restrict__ deg) {
  int e = blockIdx.x * blockDim.x + threadIdx.x;
  if (e >= EPTOT) return;
  int d = (e < EE) ? ei[EE + e] : (e - EE);
  atomicAdd(&deg[d], 1);
}

__global__ __launch_bounds__(256) void degsum_kernel(const int* __restrict__ deg,
                                                     int* __restrict__ bsum) {
  __shared__ int sh[256];
  int i = blockIdx.x * 256 + threadIdx.x;
  sh[threadIdx.x] = (i < NN) ? deg[i] : 0;
  __syncthreads();
  for (int off = 128; off > 0; off >>= 1) {
    if (threadIdx.x < off) sh[threadIdx.x] += sh[threadIdx.x + off];
    __syncthreads();
  }
  if (threadIdx.x == 0) bsum[blockIdx.x] = sh[0];
}

__global__ __launch_bounds__(256) void scanb_kernel(const int* __restrict__ bsum,
                                                    int* __restrict__ boff,
                                                    int* __restrict__ rowptr) {
  __shared__ int sh[256];
  int t = threadIdx.x;
  int v = (t < NB) ? bsum[t] : 0;
  sh[t] = v;
  __syncthreads();
  for (int off = 1; off < 256; off <<= 1) {
    int u = (t >= off) ? sh[t - off] : 0;
    __syncthreads();
    sh[t] += u;
    __syncthreads();
  }
  if (t < NB) boff[t] = sh[t] - v;
  if (t == 255) rowptr[NN] = sh[255];
}

__global__ __launch_bounds__(256) void rowptr_kernel(const int* __restrict__ deg,
                                                     const int* __restrict__ boff,
                                                     int* __restrict__ rowptr) {
  __shared__ int sh[256];
  int t = threadIdx.x;
  int i = blockIdx.x * 256 + t;
  int v = (i < NN) ? deg[i] : 0;
  sh[t] = v;
  __syncthreads();
  for (int off = 1; off < 256; off <<= 1) {
    int u = (t >= off) ? sh[t - off] : 0;
    __syncthreads();
    sh[t] += u;
    __syncthreads();
  }
  if (i < NN) rowptr[i] = boff[blockIdx.x] + sh[t] - v;
}

__global__ void bcurinit_kernel(const int* __restrict__ rowptr, int* __restrict__ bcur) {
  int b = threadIdx.x;
  if (b < NBUK) bcur[b] = rowptr[b << BSHIFT];
}

// Pass A: partition edges into dst-buckets; run-coalesced 8B pair writes.
__global__ __launch_bounds__(256) void partA_kernel(const int* __restrict__ ei,
                                                    int* __restrict__ bcur,
                                                    unsigned long long* __restrict__ pairs) {
  __shared__ int hist[NBUK];
  __shared__ int sbase[NBUK];
  int t = threadIdx.x;
  if (t < NBUK) hist[t] = 0;
  __syncthreads();
  int e0 = blockIdx.x * PCHUNK;
  int ss[16], dd[16];
  int cnt = 0;
#pragma unroll
  for (int i = 0; i < 16; ++i) {
    int e = e0 + i * 256 + t;
    if (e < EPTOT) {
      int s, d;
      if (e < EE) { s = ei[e]; d = ei[EE + e]; } else { s = e - EE; d = s; }
      ss[cnt] = s; dd[cnt] = d; ++cnt;
      atomicAdd(&hist[d >> BSHIFT], 1);
    }
  }
  __syncthreads();
  if (t < NBUK) {
    int h = hist[t];
    sbase[t] = h ? atomicAdd(&bcur[t], h) : 0;
    hist[t] = 0;
  }
  __syncthreads();
  for (int i = 0; i < cnt; ++i) {
    int b = dd[i] >> BSHIFT;
    int pos = sbase[b] + atomicAdd(&hist[b], 1);
    pairs[pos] = ((unsigned long long)(unsigned)dd[i] << 32) | (unsigned)ss[i];
  }
}

// Pass B: one block per bucket; LDS cursors + LDS colb staging; coalesced flush.
__global__ __launch_bounds__(512) void partB_kernel(const unsigned long long* __restrict__ pairs,
                                                    const int* __restrict__ rowptr,
                                                    int* __restrict__ colb) {
  __shared__ int cur[512];
  __shared__ int stage[BCAP];
  int b = blockIdx.x;
  int t = threadIdx.x;
  int node0 = b << BSHIFT;
  int node1 = min(node0 + 512, NN);
  int base = rowptr[node0];
  int nE = rowptr[node1] - base;
  cur[t] = (node0 + t < node1) ? (rowptr[node0 + t] - base) : 0;
  __syncthreads();
  for (int j = t; j < nE; j += 512) {
    unsigned long long p = pairs[base + j];
    int d = (int)(p >> 32);
    int s = (int)(p & 0xffffffffu);
    int pl = atomicAdd(&cur[d - node0], 1);
    if (pl < BCAP) stage[pl] = s;
    else colb[base + pl] = s;
  }
  __syncthreads();
  int lim = min(nE, BCAP);
  for (int j = t; j < lim; j += 512) colb[base + j] = stage[j];
}

__device__ inline float bnelu1(float v, float scale, float shift) {
  v = v * scale + shift;
  return (v > 0.f) ? v : expm1f(v);
}

// pack W[layer] (128x128 f32 row-major) into MFMA A-fragment order, f16.
__global__ __launch_bounds__(256) void prepack_kernel(const float* __restrict__ Ws,
                                                      _Float16* __restrict__ Wp) {
  int f = blockIdx.x * 256 + threadIdx.x;
  if (f >= 3 * 2048) return;
  int layer = f >> 11, r = f & 2047;
  int ctile = r >> 8, ks = (r >> 6) & 3, lane = r & 63;
  const float* W = Ws + (size_t)layer * HIDD * HIDD;
  int col = ctile * 16 + (lane & 15);
  int krow = ks * 32 + (lane >> 4) * 8;
  f16x8 v;
#pragma unroll
  for (int j = 0; j < 8; ++j) v[j] = (_Float16)W[(krow + j) * HIDD + col];
  *(f16x8*)(Wp + (size_t)f * 8) = v;
}

__global__ void bnfinal_kernel(const float* __restrict__ stat,
                               const float* __restrict__ gamma,
                               const float* __restrict__ beta,
                               float* __restrict__ scsh) {
  int c = threadIdx.x;
  const float invN = 1.f / (float)NN;
  float mean = stat[c] * invN;
  float var = stat[128 + c] * invN - mean * mean;
  float scale = gamma[c] * rsqrtf(var + 1e-5f);
  scsh[c] = scale;
  scsh[128 + c] = beta[c] - mean * scale;
}

// MFMA GEMM, operand-swapped: wave computes 16 nodes x 128 channels.
__global__ __launch_bounds__(256) void gemm_mfma_kernel(
    const float* __restrict__ X, const _Float16* __restrict__ Wp,
    const float* __restrict__ scsh, const float* __restrict__ asrc,
    const float* __restrict__ adst, __half* __restrict__ Hh,
    float* __restrict__ esrc, float* __restrict__ edst) {
  int wave = threadIdx.x >> 6, lane = threadIdx.x & 63;
  int jt = blockIdx.x * 4 + wave;
  if (jt >= NTILE) return;
  int nl = lane & 15, kg = lane >> 4;
  int node = jt * 16 + nl;
  const float* xrow = X + (size_t)node * HIDD;
  f32x4 acc[8];
#pragma unroll
  for (int c = 0; c < 8; ++c) acc[c] = (f32x4){0.f, 0.f, 0.f, 0.f};
#pragma unroll
  for (int ks = 0; ks < 4; ++ks) {
    int k0 = ks * 32 + kg * 8;
    float4 va = *(const float4*)(xrow + k0);
    float4 vb = *(const float4*)(xrow + k0 + 4);
    if (scsh) {
      float4 s0 = *(const float4*)(scsh + k0);
      float4 s1 = *(const float4*)(scsh + k0 + 4);
      float4 t0 = *(const float4*)(scsh + HIDD + k0);
      float4 t1 = *(const float4*)(scsh + HIDD + k0 + 4);
      va.x = bnelu1(va.x, s0.x, t0.x); va.y = bnelu1(va.y, s0.y, t0.y);
      va.z = bnelu1(va.z, s0.z, t0.z); va.w = bnelu1(va.w, s0.w, t0.w);
      vb.x = bnelu1(vb.x, s1.x, t1.x); vb.y = bnelu1(vb.y, s1.y, t1.y);
      vb.z = bnelu1(vb.z, s1.z, t1.z); vb.w = bnelu1(vb.w, s1.w, t1.w);
    }
    f16x8 bfrag;
    bfrag[0] = (_Float16)va.x; bfrag[1] = (_Float16)va.y;
    bfrag[2] = (_Float16)va.z; bfrag[3] = (_Float16)va.w;
    bfrag[4] = (_Float16)vb.x; bfrag[5] = (_Float16)vb.y;
    bfrag[6] = (_Float16)vb.z; bfrag[7] = (_Float16)vb.w;
#pragma unroll
    for (int c = 0; c < 8; ++c) {
      f16x8 afrag = *(const f16x8*)(Wp + (((size_t)(c * 4 + ks) * 64 + lane) << 3));
      acc[c] = __builtin_amdgcn_mfma_f32_16x16x32_f16(afrag, bfrag, acc[c], 0, 0, 0);
    }
  }
  float es_p[4] = {0.f, 0.f, 0.f, 0.f};
  float ed_p[4] = {0.f, 0.f, 0.f, 0.f};
  __half* hrow = Hh + (size_t)node * HIDD;
#pragma unroll
  for (int c = 0; c < 8; ++c) {
    int ch0 = c * 16 + kg * 4;
    __half2 h01 = __floats2half2_rn(acc[c][0], acc[c][1]);
    __half2 h23 = __floats2half2_rn(acc[c][2], acc[c][3]);
    union { __half2 h[2]; float2 f; } u;
    u.h[0] = h01; u.h[1] = h23;
    *(float2*)(hrow + ch0) = u.f;
    float4 av = *(const float4*)(asrc + ch0);
    float4 bv = *(const float4*)(adst + ch0);
    int hd = c >> 1;
    es_p[hd] += acc[c][0] * av.x + acc[c][1] * av.y + acc[c][2] * av.z + acc[c][3] * av.w;
    ed_p[hd] += acc[c][0] * bv.x + acc[c][1] * bv.y + acc[c][2] * bv.z + acc[c][3] * bv.w;
  }
#pragma unroll
  for (int hd = 0; hd < 4; ++hd) {
    es_p[hd] += __shfl_xor(es_p[hd], 16);
    es_p[hd] += __shfl_xor(es_p[hd], 32);
    ed_p[hd] += __shfl_xor(ed_p[hd], 16);
    ed_p[hd] += __shfl_xor(ed_p[hd], 32);
  }
  float es_o = (kg == 0) ? es_p[0] : (kg == 1) ? es_p[1] : (kg == 2) ? es_p[2] : es_p[3];
  float ed_o = (kg == 0) ? ed_p[0] : (kg == 1) ? ed_p[1] : (kg == 2) ? ed_p[2] : ed_p[3];
  esrc[node * 4 + kg] = es_o;
  edst[node * 4 + kg] = ed_o;
}

// one wave per dst node; lane owns channels 2l,2l+1 (head = l>>4).
// 1-deep software prefetch of (src, esrc, Hh) to raise MLP on the gather chain.
__global__ __launch_bounds__(256) void agg_kernel(const __half2* __restrict__ Hh,
                                                  const float* __restrict__ esrc,
                                                  const float* __restrict__ edst,
                                                  const int* __restrict__ rowptr,
                                                  const int* __restrict__ colb,
                                                  const float* __restrict__ bias,
                                                  float* __restrict__ out) {
  int wid = (blockIdx.x * 256 + threadIdx.x) >> 6;
  int lane = threadIdx.x & 63;
  if (wid >= NN) return;
  int hd = lane >> 4;
  float ed = edst[wid * 4 + hd];
  int e0 = rowptr[wid], e1 = rowptr[wid + 1];
  float den = 0.f, ax = 0.f, ay = 0.f;
  const __half2* hbase = Hh + lane;
  int src = colb[e0];  // every node has >=1 edge (self-loop)
  float es = esrc[src * 4 + hd];
  __half2 hv = hbase[(size_t)src * 64];
  for (int e = e0; e < e1; ++e) {
    int srcn = (e + 1 < e1) ? colb[e + 1] : src;
    float esn = esrc[srcn * 4 + hd];
    __half2 hvn = hbase[(size_t)srcn * 64];
    float z = es + ed;
    z = (z > 0.f) ? z : NEG_SLOPE * z;
    float w = __expf(z);
    float2 f = __half22float2(hv);
    den += w;
    ax += w * f.x;
    ay += w * f.y;
    src = srcn; es = esn; hv = hvn;
  }
  float inv = 1.f / (den + 1e-16f);
  int c = 2 * lane;
  out[(size_t)wid * HIDD + c] = ax * inv + bias[c];
  out[(size_t)wid * HIDD + c + 1] = ay * inv + bias[c + 1];
}

__global__ __launch_bounds__(256) void bnstat_kernel(const float* __restrict__ X,
                                                     float* __restrict__ stat) {
  __shared__ float sh[256];
  int tid = threadIdx.x;
  int c = tid & 127;
  int half = tid >> 7;
  float s = 0.f, q = 0.f;
  for (int r = blockIdx.x * 2 + half; r < NN; r += gridDim.x * 2) {
    float v = X[(size_t)r * HIDD + c];
    s += v;
    q += v * v;
  }
  sh[tid] = s;
  __syncthreads();
  if (tid < 128) atomicAdd(&stat[c], s + sh[tid + 128]);
  __syncthreads();
  sh[tid] = q;
  __syncthreads();
  if (tid < 128) atomicAdd(&stat[128 + c], q + sh[tid + 128]);
}

__global__ void gbound_kernel(const int* __restrict__ batch, int* __restrict__ gstart) {
  int i = blockIdx.x * blockDim.x + threadIdx.x;
  if (i >= NN) return;
  int cur = batch[i];
  int prev = (i == 0) ? -1 : batch[i - 1];
  for (int g = prev + 1; g <= cur; ++g) gstart[g] = i;
  if (i == NN - 1) {
    for (int g = cur + 1; g <= GG; ++g) gstart[g] = NN;
  }
}

__global__ __launch_bounds__(128) void pool_kernel(const float* __restrict__ X,
                                                   const int* __restrict__ gstart,
                                                   const float* __restrict__ scsh,
                                                   float* __restrict__ pooled) {
  int g = blockIdx.x;
  int c = threadIdx.x;
  float scale = scsh[c];
  float shift = scsh[128 + c];
  int n0 = gstart[g], n1 = gstart[g + 1];
  float s = 0.f;
  for (int n = n0; n < n1; ++n) s += bnelu1(X[(size_t)n * HIDD + c], scale, shift);
  float inv = (n1 > n0) ? 1.f / (float)(n1 - n0) : 0.f;
  pooled[(size_t)g * HIDD + c] = s * inv;
}

__global__ __launch_bounds__(256) void head_kernel(const float* __restrict__ pooled,
                                                   const float* __restrict__ w1,
                                                   const float* __restrict__ b1,
                                                   const float* __restrict__ w2,
                                                   const float* __restrict__ b2,
                                                   float* __restrict__ out) {
  int wid = (blockIdx.x * 256 + threadIdx.x) >> 6;
  int lane = threadIdx.x & 63;
  if (wid >= GG) return;
  float acc = b1[lane];
  const float* pg = pooled + (size_t)wid * HIDD;
  for (int k = 0; k < HIDD; ++k) {
    acc += pg[k] * w1[k * 64 + lane];
  }
  acc = fmaxf(acc, 0.f);
  float v = acc * w2[lane];
#pragma unroll
  for (int off = 32; off > 0; off >>= 1) v += __shfl_down(v, off);
  if (lane == 0) out[wid] = v + b2[0];
}

extern "C" void kernel_launch(void* const* d_in, const int* in_sizes, int n_in,
                              void* d_out, int out_size, void* d_ws, size_t ws_size,
                              hipStream_t stream) {
  const float* x    = (const float*)d_in[0];
  const int* ei     = (const int*)d_in[1];
  const int* batch  = (const int*)d_in[2];
  const float* Ws   = (const float*)d_in[3];
  const float* asrc = (const float*)d_in[4];
  const float* adst = (const float*)d_in[5];
  const float* bias = (const float*)d_in[6];
  const float* gam  = (const float*)d_in[7];
  const float* bet  = (const float*)d_in[8];
  const float* w1   = (const float*)d_in[9];
  const float* b1   = (const float*)d_in[10];
  const float* w2   = (const float*)d_in[11];
  const float* b2   = (const float*)d_in[12];
  float* out = (float*)d_out;

  char* wp = (char*)d_ws;
  auto carve = [&](size_t bytes) -> char* {
    char* p = wp;
    wp += (bytes + 255) & ~(size_t)255;
    return p;
  };
  float* B      = (float*)carve((size_t)NN * HIDD * 4);
  __half* Hh    = (__half*)carve((size_t)NN * HIDD * 2);
  _Float16* Wp  = (_Float16*)carve((size_t)3 * HIDD * HIDD * 2);
  float* scsh   = (float*)carve((size_t)3 * 256 * 4);
  float* esrc   = (float*)carve((size_t)NN * NHEAD * 4);
  float* edst   = (float*)carve((size_t)NN * NHEAD * 4);
  int* rowptr   = (int*)carve((size_t)(NN + 1) * 4);
  int* colb     = (int*)carve((size_t)EPTOT * 4);
  unsigned long long* pairs = (unsigned long long*)carve((size_t)EPTOT * 8);
  int* bcur     = (int*)carve((size_t)NBUK * 4);
  int* bsum     = (int*)carve((size_t)NB * 4);
  int* boff     = (int*)carve((size_t)NB * 4);
  int* gstart   = (int*)carve((size_t)(GG + 1) * 4);
  float* pooled = (float*)carve((size_t)GG * HIDD * 4);
  char* z0 = wp;
  int* deg      = (int*)carve((size_t)NN * 4);
  float* stats  = (float*)carve(768 * 4);
  int zcount = (int)((wp - z0) / 4);

  zero_kernel<<<(zcount + 255) / 256, 256, 0, stream>>>((float*)z0, zcount);
  prepack_kernel<<<24, 256, 0, stream>>>(Ws, Wp);
  count_kernel<<<(EPTOT + 255) / 256, 256, 0, stream>>>(ei, deg);
  degsum_kernel<<<NB, 256, 0, stream>>>(deg, bsum);
  scanb_kernel<<<1, 256, 0, stream>>>(bsum, boff, rowptr);
  rowptr_kernel<<<NB, 256, 0, stream>>>(deg, boff, rowptr);
  bcurinit_kernel<<<1, 128, 0, stream>>>(rowptr, bcur);
  partA_kernel<<<(EPTOT + PCHUNK - 1) / PCHUNK, 256, 0, stream>>>(ei, bcur, pairs);
  partB_kernel<<<NBUK, 512, 0, stream>>>(pairs, rowptr, colb);
  gbound_kernel<<<(NN + 255) / 256, 256, 0, stream>>>(batch, gstart);

  const float* xin = x;
  for (int l = 0; l < 3; ++l) {
    const float* sc_prev = (l == 0) ? nullptr : scsh + (l - 1) * 256;
    gemm_mfma_kernel<<<(NTILE + 3) / 4, 256, 0, stream>>>(
        xin, Wp + (size_t)l * HIDD * HIDD, sc_prev,
        asrc + l * NHEAD * 32, adst + l * NHEAD * 32, Hh, esrc, edst);
    agg_kernel<<<(NN * 64 + 255) / 256, 256, 0, stream>>>(
        (const __half2*)Hh, esrc, edst, rowptr, colb, bias + l * HIDD, B);
    bnstat_kernel<<<256, 256, 0, stream>>>(B, stats + l * 256);
    bnfinal_kernel<<<1, 128, 0, stream>>>(stats + l * 256, gam + l * HIDD,
                                          bet + l * HIDD, scsh + l * 256);
    xin = B;
  }
  pool_kernel<<<GG, 128, 0, stream>>>(B, gstart, scsh + 2 * 256, pooled);
  head_kernel<<<(GG * 64 + 255) / 256, 256, 0, stream>>>(pooled, w1, b1, w2, b2, out);
}

// Round 6
// 406.983 us; speedup vs baseline: 2.0886x; 1.1068x over previous
//
#include <hip/hip_runtime.h>
#include <hip/hip_fp16.h>
#include <math.h>

#define NN 50000
#define EE 800000
#define GG 1024
#define HIDD 128
#define NHEAD 4
#define EPTOT (EE + NN)
#define NEG_SLOPE 0.2f
#define NB ((NN + 255) / 256)
#define NTILE (NN / 16)  // 3125 wave-tiles, exact

#define BSHIFT 9          // 512 nodes per bucket
#define NBUK 98           // ceil(50000/512)
#define PCHUNK 4096       // edges per partition block
#define BCAP 10240        // staged colb entries per bucket

typedef _Float16 f16x8 __attribute__((ext_vector_type(8)));
typedef float f32x4 __attribute__((ext_vector_type(4)));

__global__ void zero_kernel(float* __restrict__ p, int n) {
  int i = blockIdx.x * blockDim.x + threadIdx.x;
  if (i < n) p[i] = 0.f;
}

__global__ void count_kernel(const int* __restrict__ ei, int* __restrict__ deg) {
  int e = blockIdx.x * blockDim.x + threadIdx.x;
  if (e >= EPTOT) return;
  int d = (e < EE) ? ei[EE + e] : (e - EE);
  atomicAdd(&deg[d], 1);
}

__global__ __launch_bounds__(256) void degsum_kernel(const int* __restrict__ deg,
                                                     int* __restrict__ bsum) {
  __shared__ int sh[256];
  int i = blockIdx.x * 256 + threadIdx.x;
  sh[threadIdx.x] = (i < NN) ? deg[i] : 0;
  __syncthreads();
  for (int off = 128; off > 0; off >>= 1) {
    if (threadIdx.x < off) sh[threadIdx.x] += sh[threadIdx.x + off];
    __syncthreads();
  }
  if (threadIdx.x == 0) bsum[blockIdx.x] = sh[0];
}

__global__ __launch_bounds__(256) void scanb_kernel(const int* __restrict__ bsum,
                                                    int* __restrict__ boff,
                                                    int* __restrict__ rowptr) {
  __shared__ int sh[256];
  int t = threadIdx.x;
  int v = (t < NB) ? bsum[t] : 0;
  sh[t] = v;
  __syncthreads();
  for (int off = 1; off < 256; off <<= 1) {
    int u = (t >= off) ? sh[t - off] : 0;
    __syncthreads();
    sh[t] += u;
    __syncthreads();
  }
  if (t < NB) boff[t] = sh[t] - v;
  if (t == 255) rowptr[NN] = sh[255];
}

__global__ __launch_bounds__(256) void rowptr_kernel(const int* __restrict__ deg,
                                                     const int* __restrict__ boff,
                                                     int* __restrict__ rowptr) {
  __shared__ int sh[256];
  int t = threadIdx.x;
  int i = blockIdx.x * 256 + t;
  int v = (i < NN) ? deg[i] : 0;
  sh[t] = v;
  __syncthreads();
  for (int off = 1; off < 256; off <<= 1) {
    int u = (t >= off) ? sh[t - off] : 0;
    __syncthreads();
    sh[t] += u;
    __syncthreads();
  }
  if (i < NN) rowptr[i] = boff[blockIdx.x] + sh[t] - v;
}

__global__ void bcurinit_kernel(const int* __restrict__ rowptr, int* __restrict__ bcur) {
  int b = threadIdx.x;
  if (b < NBUK) bcur[b] = rowptr[b << BSHIFT];
}

// Pass A: partition edges into dst-buckets; run-coalesced 8B pair writes.
__global__ __launch_bounds__(256) void partA_kernel(const int* __restrict__ ei,
                                                    int* __restrict__ bcur,
                                                    unsigned long long* __restrict__ pairs) {
  __shared__ int hist[NBUK];
  __shared__ int sbase[NBUK];
  int t = threadIdx.x;
  if (t < NBUK) hist[t] = 0;
  __syncthreads();
  int e0 = blockIdx.x * PCHUNK;
  int ss[16], dd[16];
  int cnt = 0;
#pragma unroll
  for (int i = 0; i < 16; ++i) {
    int e = e0 + i * 256 + t;
    if (e < EPTOT) {
      int s, d;
      if (e < EE) { s = ei[e]; d = ei[EE + e]; } else { s = e - EE; d = s; }
      ss[cnt] = s; dd[cnt] = d; ++cnt;
      atomicAdd(&hist[d >> BSHIFT], 1);
    }
  }
  __syncthreads();
  if (t < NBUK) {
    int h = hist[t];
    sbase[t] = h ? atomicAdd(&bcur[t], h) : 0;
    hist[t] = 0;
  }
  __syncthreads();
  for (int i = 0; i < cnt; ++i) {
    int b = dd[i] >> BSHIFT;
    int pos = sbase[b] + atomicAdd(&hist[b], 1);
    pairs[pos] = ((unsigned long long)(unsigned)dd[i] << 32) | (unsigned)ss[i];
  }
}

// Pass B: one block per bucket; LDS cursors + LDS colb staging; coalesced flush.
__global__ __launch_bounds__(512) void partB_kernel(const unsigned long long* __restrict__ pairs,
                                                    const int* __restrict__ rowptr,
                                                    int* __restrict__ colb) {
  __shared__ int cur[512];
  __shared__ int stage[BCAP];
  int b = blockIdx.x;
  int t = threadIdx.x;
  int node0 = b << BSHIFT;
  int node1 = min(node0 + 512, NN);
  int base = rowptr[node0];
  int nE = rowptr[node1] - base;
  cur[t] = (node0 + t < node1) ? (rowptr[node0 + t] - base) : 0;
  __syncthreads();
  for (int j = t; j < nE; j += 512) {
    unsigned long long p = pairs[base + j];
    int d = (int)(p >> 32);
    int s = (int)(p & 0xffffffffu);
    int pl = atomicAdd(&cur[d - node0], 1);
    if (pl < BCAP) stage[pl] = s;
    else colb[base + pl] = s;
  }
  __syncthreads();
  int lim = min(nE, BCAP);
  for (int j = t; j < lim; j += 512) colb[base + j] = stage[j];
}

__device__ inline float bnelu1(float v, float scale, float shift) {
  v = v * scale + shift;
  return (v > 0.f) ? v : expm1f(v);
}

// pack W[layer] (128x128 f32 row-major) into MFMA A-fragment order, f16.
__global__ __launch_bounds__(256) void prepack_kernel(const float* __restrict__ Ws,
                                                      _Float16* __restrict__ Wp) {
  int f = blockIdx.x * 256 + threadIdx.x;
  if (f >= 3 * 2048) return;
  int layer = f >> 11, r = f & 2047;
  int ctile = r >> 8, ks = (r >> 6) & 3, lane = r & 63;
  const float* W = Ws + (size_t)layer * HIDD * HIDD;
  int col = ctile * 16 + (lane & 15);
  int krow = ks * 32 + (lane >> 4) * 8;
  f16x8 v;
#pragma unroll
  for (int j = 0; j < 8; ++j) v[j] = (_Float16)W[(krow + j) * HIDD + col];
  *(f16x8*)(Wp + (size_t)f * 8) = v;
}

__global__ void bnfinal_kernel(const float* __restrict__ stat,
                               const float* __restrict__ gamma,
                               const float* __restrict__ beta,
                               float* __restrict__ scsh) {
  int c = threadIdx.x;
  const float invN = 1.f / (float)NN;
  float mean = stat[c] * invN;
  float var = stat[128 + c] * invN - mean * mean;
  float scale = gamma[c] * rsqrtf(var + 1e-5f);
  scsh[c] = scale;
  scsh[128 + c] = beta[c] - mean * scale;
}

// MFMA GEMM, operand-swapped: wave computes 16 nodes x 128 channels.
// Layer 0 reads f32 x (no BN); layers 1,2 read f16 B with fused BN+ELU.
__global__ __launch_bounds__(256) void gemm_mfma_kernel(
    const float* __restrict__ Xf, const __half* __restrict__ Xh,
    const _Float16* __restrict__ Wp, const float* __restrict__ scsh,
    const float* __restrict__ asrc, const float* __restrict__ adst,
    __half* __restrict__ Hh, float* __restrict__ esrc, float* __restrict__ edst) {
  int wave = threadIdx.x >> 6, lane = threadIdx.x & 63;
  int jt = blockIdx.x * 4 + wave;
  if (jt >= NTILE) return;
  int nl = lane & 15, kg = lane >> 4;
  int node = jt * 16 + nl;
  f32x4 acc[8];
#pragma unroll
  for (int c = 0; c < 8; ++c) acc[c] = (f32x4){0.f, 0.f, 0.f, 0.f};
#pragma unroll
  for (int ks = 0; ks < 4; ++ks) {
    int k0 = ks * 32 + kg * 8;
    f16x8 bfrag;
    if (Xf) {
      const float* xrow = Xf + (size_t)node * HIDD;
      float4 va = *(const float4*)(xrow + k0);
      float4 vb = *(const float4*)(xrow + k0 + 4);
      bfrag[0] = (_Float16)va.x; bfrag[1] = (_Float16)va.y;
      bfrag[2] = (_Float16)va.z; bfrag[3] = (_Float16)va.w;
      bfrag[4] = (_Float16)vb.x; bfrag[5] = (_Float16)vb.y;
      bfrag[6] = (_Float16)vb.z; bfrag[7] = (_Float16)vb.w;
    } else {
      const __half2* xrow = (const __half2*)(Xh + (size_t)node * HIDD + k0);
      float4 s0 = *(const float4*)(scsh + k0);
      float4 s1 = *(const float4*)(scsh + k0 + 4);
      float4 t0 = *(const float4*)(scsh + HIDD + k0);
      float4 t1 = *(const float4*)(scsh + HIDD + k0 + 4);
      float2 f0 = __half22float2(xrow[0]);
      float2 f1 = __half22float2(xrow[1]);
      float2 f2 = __half22float2(xrow[2]);
      float2 f3 = __half22float2(xrow[3]);
      bfrag[0] = (_Float16)bnelu1(f0.x, s0.x, t0.x);
      bfrag[1] = (_Float16)bnelu1(f0.y, s0.y, t0.y);
      bfrag[2] = (_Float16)bnelu1(f1.x, s0.z, t0.z);
      bfrag[3] = (_Float16)bnelu1(f1.y, s0.w, t0.w);
      bfrag[4] = (_Float16)bnelu1(f2.x, s1.x, t1.x);
      bfrag[5] = (_Float16)bnelu1(f2.y, s1.y, t1.y);
      bfrag[6] = (_Float16)bnelu1(f3.x, s1.z, t1.z);
      bfrag[7] = (_Float16)bnelu1(f3.y, s1.w, t1.w);
    }
#pragma unroll
    for (int c = 0; c < 8; ++c) {
      f16x8 afrag = *(const f16x8*)(Wp + (((size_t)(c * 4 + ks) * 64 + lane) << 3));
      acc[c] = __builtin_amdgcn_mfma_f32_16x16x32_f16(afrag, bfrag, acc[c], 0, 0, 0);
    }
  }
  float es_p[4] = {0.f, 0.f, 0.f, 0.f};
  float ed_p[4] = {0.f, 0.f, 0.f, 0.f};
  __half* hrow = Hh + (size_t)node * HIDD;
#pragma unroll
  for (int c = 0; c < 8; ++c) {
    int ch0 = c * 16 + kg * 4;
    __half2 h01 = __floats2half2_rn(acc[c][0], acc[c][1]);
    __half2 h23 = __floats2half2_rn(acc[c][2], acc[c][3]);
    union { __half2 h[2]; float2 f; } u;
    u.h[0] = h01; u.h[1] = h23;
    *(float2*)(hrow + ch0) = u.f;
    float4 av = *(const float4*)(asrc + ch0);
    float4 bv = *(const float4*)(adst + ch0);
    int hd = c >> 1;
    es_p[hd] += acc[c][0] * av.x + acc[c][1] * av.y + acc[c][2] * av.z + acc[c][3] * av.w;
    ed_p[hd] += acc[c][0] * bv.x + acc[c][1] * bv.y + acc[c][2] * bv.z + acc[c][3] * bv.w;
  }
#pragma unroll
  for (int hd = 0; hd < 4; ++hd) {
    es_p[hd] += __shfl_xor(es_p[hd], 16);
    es_p[hd] += __shfl_xor(es_p[hd], 32);
    ed_p[hd] += __shfl_xor(ed_p[hd], 16);
    ed_p[hd] += __shfl_xor(ed_p[hd], 32);
  }
  float es_o = (kg == 0) ? es_p[0] : (kg == 1) ? es_p[1] : (kg == 2) ? es_p[2] : es_p[3];
  float ed_o = (kg == 0) ? ed_p[0] : (kg == 1) ? ed_p[1] : (kg == 2) ? ed_p[2] : ed_p[3];
  esrc[node * 4 + kg] = es_o;
  edst[node * 4 + kg] = ed_o;
}

// one wave per dst node; lane owns channels 2l,2l+1 (head = l>>4).
// 4-wide edge batching: 4 colb loads, then 4 independent (esrc, Hh) gather
// pairs in flight -> MLP=4 on the latency-bound chain. f16 output.
__global__ __launch_bounds__(256) void agg_kernel(const __half2* __restrict__ Hh,
                                                  const float* __restrict__ esrc,
                                                  const float* __restrict__ edst,
                                                  const int* __restrict__ rowptr,
                                                  const int* __restrict__ colb,
                                                  const float* __restrict__ bias,
                                                  __half* __restrict__ outh) {
  int wid = (blockIdx.x * 256 + threadIdx.x) >> 6;
  int lane = threadIdx.x & 63;
  if (wid >= NN) return;
  int hd = lane >> 4;
  float ed = edst[wid * 4 + hd];
  int e0 = rowptr[wid], e1 = rowptr[wid + 1];
  float den = 0.f, ax = 0.f, ay = 0.f;
  const __half2* hbase = Hh + lane;
  int e = e0;
  for (; e + 4 <= e1; e += 4) {
    int s[4];
#pragma unroll
    for (int j = 0; j < 4; ++j) s[j] = colb[e + j];
    float es[4];
    __half2 hv[4];
#pragma unroll
    for (int j = 0; j < 4; ++j) {
      es[j] = esrc[s[j] * 4 + hd];
      hv[j] = hbase[(size_t)s[j] * 64];
    }
#pragma unroll
    for (int j = 0; j < 4; ++j) {
      float z = es[j] + ed;
      z = fmaxf(z, NEG_SLOPE * z);
      float w = __expf(z);
      float2 f = __half22float2(hv[j]);
      den += w;
      ax += w * f.x;
      ay += w * f.y;
    }
  }
  for (; e < e1; ++e) {
    int src = colb[e];
    float esv = esrc[src * 4 + hd];
    __half2 hvv = hbase[(size_t)src * 64];
    float z = esv + ed;
    z = fmaxf(z, NEG_SLOPE * z);
    float w = __expf(z);
    float2 f = __half22float2(hvv);
    den += w;
    ax += w * f.x;
    ay += w * f.y;
  }
  float inv = 1.f / (den + 1e-16f);
  int c = 2 * lane;
  float vx = ax * inv + bias[c];
  float vy = ay * inv + bias[c + 1];
  *((__half2*)(outh + (size_t)wid * HIDD) + lane) = __floats2half2_rn(vx, vy);
}

__global__ __launch_bounds__(256) void bnstat_kernel(const __half* __restrict__ X,
                                                     float* __restrict__ stat) {
  __shared__ float sh[256];
  int tid = threadIdx.x;
  int c = tid & 127;
  int half = tid >> 7;
  float s = 0.f, q = 0.f;
  for (int r = blockIdx.x * 2 + half; r < NN; r += gridDim.x * 2) {
    float v = __half2float(X[(size_t)r * HIDD + c]);
    s += v;
    q += v * v;
  }
  sh[tid] = s;
  __syncthreads();
  if (tid < 128) atomicAdd(&stat[c], s + sh[tid + 128]);
  __syncthreads();
  sh[tid] = q;
  __syncthreads();
  if (tid < 128) atomicAdd(&stat[128 + c], q + sh[tid + 128]);
}

__global__ void gbound_kernel(const int* __restrict__ batch, int* __restrict__ gstart) {
  int i = blockIdx.x * blockDim.x + threadIdx.x;
  if (i >= NN) return;
  int cur = batch[i];
  int prev = (i == 0) ? -1 : batch[i - 1];
  for (int g = prev + 1; g <= cur; ++g) gstart[g] = i;
  if (i == NN - 1) {
    for (int g = cur + 1; g <= GG; ++g) gstart[g] = NN;
  }
}

__global__ __launch_bounds__(128) void pool_kernel(const __half* __restrict__ X,
                                                   const int* __restrict__ gstart,
                                                   const float* __restrict__ scsh,
                                                   float* __restrict__ pooled) {
  int g = blockIdx.x;
  int c = threadIdx.x;
  float scale = scsh[c];
  float shift = scsh[128 + c];
  int n0 = gstart[g], n1 = gstart[g + 1];
  float s = 0.f;
  for (int n = n0; n < n1; ++n)
    s += bnelu1(__half2float(X[(size_t)n * HIDD + c]), scale, shift);
  float inv = (n1 > n0) ? 1.f / (float)(n1 - n0) : 0.f;
  pooled[(size_t)g * HIDD + c] = s * inv;
}

__global__ __launch_bounds__(256) void head_kernel(const float* __restrict__ pooled,
                                                   const float* __restrict__ w1,
                                                   const float* __restrict__ b1,
                                                   const float* __restrict__ w2,
                                                   const float* __restrict__ b2,
                                                   float* __restrict__ out) {
  int wid = (blockIdx.x * 256 + threadIdx.x) >> 6;
  int lane = threadIdx.x & 63;
  if (wid >= GG) return;
  float acc = b1[lane];
  const float* pg = pooled + (size_t)wid * HIDD;
  for (int k = 0; k < HIDD; ++k) {
    acc += pg[k] * w1[k * 64 + lane];
  }
  acc = fmaxf(acc, 0.f);
  float v = acc * w2[lane];
#pragma unroll
  for (int off = 32; off > 0; off >>= 1) v += __shfl_down(v, off);
  if (lane == 0) out[wid] = v + b2[0];
}

extern "C" void kernel_launch(void* const* d_in, const int* in_sizes, int n_in,
                              void* d_out, int out_size, void* d_ws, size_t ws_size,
                              hipStream_t stream) {
  const float* x    = (const float*)d_in[0];
  const int* ei     = (const int*)d_in[1];
  const int* batch  = (const int*)d_in[2];
  const float* Ws   = (const float*)d_in[3];
  const float* asrc = (const float*)d_in[4];
  const float* adst = (const float*)d_in[5];
  const float* bias = (const float*)d_in[6];
  const float* gam  = (const float*)d_in[7];
  const float* bet  = (const float*)d_in[8];
  const float* w1   = (const float*)d_in[9];
  const float* b1   = (const float*)d_in[10];
  const float* w2   = (const float*)d_in[11];
  const float* b2   = (const float*)d_in[12];
  float* out = (float*)d_out;

  char* wp = (char*)d_ws;
  auto carve = [&](size_t bytes) -> char* {
    char* p = wp;
    wp += (bytes + 255) & ~(size_t)255;
    return p;
  };
  __half* B     = (__half*)carve((size_t)NN * HIDD * 2);
  __half* Hh    = (__half*)carve((size_t)NN * HIDD * 2);
  _Float16* Wp  = (_Float16*)carve((size_t)3 * HIDD * HIDD * 2);
  float* scsh   = (float*)carve((size_t)3 * 256 * 4);
  float* esrc   = (float*)carve((size_t)NN * NHEAD * 4);
  float* edst   = (float*)carve((size_t)NN * NHEAD * 4);
  int* rowptr   = (int*)carve((size_t)(NN + 1) * 4);
  int* colb     = (int*)carve((size_t)EPTOT * 4);
  unsigned long long* pairs = (unsigned long long*)carve((size_t)EPTOT * 8);
  int* bcur     = (int*)carve((size_t)NBUK * 4);
  int* bsum     = (int*)carve((size_t)NB * 4);
  int* boff     = (int*)carve((size_t)NB * 4);
  int* gstart   = (int*)carve((size_t)(GG + 1) * 4);
  float* pooled = (float*)carve((size_t)GG * HIDD * 4);
  char* z0 = wp;
  int* deg      = (int*)carve((size_t)NN * 4);
  float* stats  = (float*)carve(768 * 4);
  int zcount = (int)((wp - z0) / 4);

  zero_kernel<<<(zcount + 255) / 256, 256, 0, stream>>>((float*)z0, zcount);
  prepack_kernel<<<24, 256, 0, stream>>>(Ws, Wp);
  count_kernel<<<(EPTOT + 255) / 256, 256, 0, stream>>>(ei, deg);
  degsum_kernel<<<NB, 256, 0, stream>>>(deg, bsum);
  scanb_kernel<<<1, 256, 0, stream>>>(bsum, boff, rowptr);
  rowptr_kernel<<<NB, 256, 0, stream>>>(deg, boff, rowptr);
  bcurinit_kernel<<<1, 128, 0, stream>>>(rowptr, bcur);
  partA_kernel<<<(EPTOT + PCHUNK - 1) / PCHUNK, 256, 0, stream>>>(ei, bcur, pairs);
  partB_kernel<<<NBUK, 512, 0, stream>>>(pairs, rowptr, colb);
  gbound_kernel<<<(NN + 255) / 256, 256, 0, stream>>>(batch, gstart);

  for (int l = 0; l < 3; ++l) {
    const float* sc_prev = (l == 0) ? nullptr : scsh + (l - 1) * 256;
    const float* xf = (l == 0) ? x : nullptr;
    const __half* xh = (l == 0) ? nullptr : B;
    gemm_mfma_kernel<<<(NTILE + 3) / 4, 256, 0, stream>>>(
        xf, xh, Wp + (size_t)l * HIDD * HIDD, sc_prev,
        asrc + l * NHEAD * 32, adst + l * NHEAD * 32, Hh, esrc, edst);
    agg_kernel<<<(NN * 64 + 255) / 256, 256, 0, stream>>>(
        (const __half2*)Hh, esrc, edst, rowptr, colb, bias + l * HIDD, B);
    bnstat_kernel<<<1024, 256, 0, stream>>>(B, stats + l * 256);
    bnfinal_kernel<<<1, 128, 0, stream>>>(stats + l * 256, gam + l * HIDD,
                                          bet + l * HIDD, scsh + l * 256);
  }
  pool_kernel<<<GG, 128, 0, stream>>>(B, gstart, scsh + 2 * 256, pooled);
  head_kernel<<<(GG * 64 + 255) / 256, 256, 0, stream>>>(pooled, w1, b1, w2, b2, out);
}

// Round 7
// 392.590 us; speedup vs baseline: 2.1652x; 1.0367x over previous
//
#include <hip/hip_runtime.h>
#include <hip/hip_fp16.h>
#include <math.h>

#define NN 50000
#define EE 800000
#define GG 1024
#define HIDD 128
#define NHEAD 4
#define EPTOT (EE + NN)
#define NEG_SLOPE 0.2f
#define NB ((NN + 255) / 256)
#define NTILE (NN / 16)  // 3125 wave-tiles, exact
#define LOG2E 1.4426950408889634f

#define BSHIFT 9          // 512 nodes per bucket
#define NBUK 98           // ceil(50000/512)
#define PCHUNK 4096       // edges per partition block
#define BCAP 10240        // staged colb entries per bucket

typedef _Float16 f16x8 __attribute__((ext_vector_type(8)));
typedef float f32x4 __attribute__((ext_vector_type(4)));

__global__ void zero_kernel(float* __restrict__ p, int n) {
  int i = blockIdx.x * blockDim.x + threadIdx.x;
  if (i < n) p[i] = 0.f;
}

__global__ void count_kernel(const int* __restrict__ ei, int* __restrict__ deg) {
  int e = blockIdx.x * blockDim.x + threadIdx.x;
  if (e >= EPTOT) return;
  int d = (e < EE) ? ei[EE + e] : (e - EE);
  atomicAdd(&deg[d], 1);
}

__global__ __launch_bounds__(256) void degsum_kernel(const int* __restrict__ deg,
                                                     int* __restrict__ bsum) {
  __shared__ int sh[256];
  int i = blockIdx.x * 256 + threadIdx.x;
  sh[threadIdx.x] = (i < NN) ? deg[i] : 0;
  __syncthreads();
  for (int off = 128; off > 0; off >>= 1) {
    if (threadIdx.x < off) sh[threadIdx.x] += sh[threadIdx.x + off];
    __syncthreads();
  }
  if (threadIdx.x == 0) bsum[blockIdx.x] = sh[0];
}

// scan block sums; also emits bcur[b] = rowptr[b*512] = exclusive prefix at 2b
__global__ __launch_bounds__(256) void scanb_kernel(const int* __restrict__ bsum,
                                                    int* __restrict__ boff,
                                                    int* __restrict__ rowptr,
                                                    int* __restrict__ bcur) {
  __shared__ int sh[256];
  int t = threadIdx.x;
  int v = (t < NB) ? bsum[t] : 0;
  sh[t] = v;
  __syncthreads();
  for (int off = 1; off < 256; off <<= 1) {
    int u = (t >= off) ? sh[t - off] : 0;
    __syncthreads();
    sh[t] += u;
    __syncthreads();
  }
  if (t < NB) boff[t] = sh[t] - v;
  if (!(t & 1) && (t >> 1) < NBUK) bcur[t >> 1] = sh[t] - v;
  if (t == 255) rowptr[NN] = sh[255];
}

__global__ __launch_bounds__(256) void rowptr_kernel(const int* __restrict__ deg,
                                                     const int* __restrict__ boff,
                                                     int* __restrict__ rowptr) {
  __shared__ int sh[256];
  int t = threadIdx.x;
  int i = blockIdx.x * 256 + t;
  int v = (i < NN) ? deg[i] : 0;
  sh[t] = v;
  __syncthreads();
  for (int off = 1; off < 256; off <<= 1) {
    int u = (t >= off) ? sh[t - off] : 0;
    __syncthreads();
    sh[t] += u;
    __syncthreads();
  }
  if (i < NN) rowptr[i] = boff[blockIdx.x] + sh[t] - v;
}

// Pass A: partition edges into dst-buckets; run-coalesced 8B pair writes.
__global__ __launch_bounds__(256) void partA_kernel(const int* __restrict__ ei,
                                                    int* __restrict__ bcur,
                                                    unsigned long long* __restrict__ pairs) {
  __shared__ int hist[NBUK];
  __shared__ int sbase[NBUK];
  int t = threadIdx.x;
  if (t < NBUK) hist[t] = 0;
  __syncthreads();
  int e0 = blockIdx.x * PCHUNK;
  int ss[16], dd[16];
  int cnt = 0;
#pragma unroll
  for (int i = 0; i < 16; ++i) {
    int e = e0 + i * 256 + t;
    if (e < EPTOT) {
      int s, d;
      if (e < EE) { s = ei[e]; d = ei[EE + e]; } else { s = e - EE; d = s; }
      ss[cnt] = s; dd[cnt] = d; ++cnt;
      atomicAdd(&hist[d >> BSHIFT], 1);
    }
  }
  __syncthreads();
  if (t < NBUK) {
    int h = hist[t];
    sbase[t] = h ? atomicAdd(&bcur[t], h) : 0;
    hist[t] = 0;
  }
  __syncthreads();
  for (int i = 0; i < cnt; ++i) {
    int b = dd[i] >> BSHIFT;
    int pos = sbase[b] + atomicAdd(&hist[b], 1);
    pairs[pos] = ((unsigned long long)(unsigned)dd[i] << 32) | (unsigned)ss[i];
  }
}

// Pass B: one block per bucket; LDS cursors + LDS colb staging; coalesced flush.
__global__ __launch_bounds__(512) void partB_kernel(const unsigned long long* __restrict__ pairs,
                                                    const int* __restrict__ rowptr,
                                                    int* __restrict__ colb) {
  __shared__ int cur[512];
  __shared__ int stage[BCAP];
  int b = blockIdx.x;
  int t = threadIdx.x;
  int node0 = b << BSHIFT;
  int node1 = min(node0 + 512, NN);
  int base = rowptr[node0];
  int nE = rowptr[node1] - base;
  cur[t] = (node0 + t < node1) ? (rowptr[node0 + t] - base) : 0;
  __syncthreads();
  for (int j = t; j < nE; j += 512) {
    unsigned long long p = pairs[base + j];
    int d = (int)(p >> 32);
    int s = (int)(p & 0xffffffffu);
    int pl = atomicAdd(&cur[d - node0], 1);
    if (pl < BCAP) stage[pl] = s;
    else colb[base + pl] = s;
  }
  __syncthreads();
  int lim = min(nE, BCAP);
  for (int j = t; j < lim; j += 512) colb[base + j] = stage[j];
}

__device__ inline float bnelu1(float v, float scale, float shift) {
  v = v * scale + shift;
  return (v > 0.f) ? v : expm1f(v);
}

// pack W[layer] (128x128 f32 row-major) into MFMA A-fragment order, f16.
__global__ __launch_bounds__(256) void prepack_kernel(const float* __restrict__ Ws,
                                                      _Float16* __restrict__ Wp) {
  int f = blockIdx.x * 256 + threadIdx.x;
  if (f >= 3 * 2048) return;
  int layer = f >> 11, r = f & 2047;
  int ctile = r >> 8, ks = (r >> 6) & 3, lane = r & 63;
  const float* W = Ws + (size_t)layer * HIDD * HIDD;
  int col = ctile * 16 + (lane & 15);
  int krow = ks * 32 + (lane >> 4) * 8;
  f16x8 v;
#pragma unroll
  for (int j = 0; j < 8; ++j) v[j] = (_Float16)W[(krow + j) * HIDD + col];
  *(f16x8*)(Wp + f * 8) = v;
}

__global__ void bnfinal_kernel(const float* __restrict__ stat,
                               const float* __restrict__ gamma,
                               const float* __restrict__ beta,
                               float* __restrict__ scsh) {
  int c = threadIdx.x;
  const float invN = 1.f / (float)NN;
  float mean = stat[c] * invN;
  float var = stat[128 + c] * invN - mean * mean;
  float scale = gamma[c] * rsqrtf(var + 1e-5f);
  scsh[c] = scale;
  scsh[128 + c] = beta[c] - mean * scale;
}

// MFMA GEMM, operand-swapped: wave computes 16 nodes x 128 channels.
// Layer 0 reads f32 x (no BN); layers 1,2 read f16 B with fused BN+ELU.
// Attention logits written pre-scaled by log2e (agg uses exp2).
__global__ __launch_bounds__(256) void gemm_mfma_kernel(
    const float* __restrict__ Xf, const __half* __restrict__ Xh,
    const _Float16* __restrict__ Wp, const float* __restrict__ scsh,
    const float* __restrict__ asrc, const float* __restrict__ adst,
    __half* __restrict__ Hh, float* __restrict__ esrc, float* __restrict__ edst) {
  int wave = threadIdx.x >> 6, lane = threadIdx.x & 63;
  int jt = blockIdx.x * 4 + wave;
  if (jt >= NTILE) return;
  int nl = lane & 15, kg = lane >> 4;
  int node = jt * 16 + nl;
  f32x4 acc[8];
#pragma unroll
  for (int c = 0; c < 8; ++c) acc[c] = (f32x4){0.f, 0.f, 0.f, 0.f};
#pragma unroll
  for (int ks = 0; ks < 4; ++ks) {
    int k0 = ks * 32 + kg * 8;
    f16x8 bfrag;
    if (Xf) {
      const float* xrow = Xf + node * HIDD;
      float4 va = *(const float4*)(xrow + k0);
      float4 vb = *(const float4*)(xrow + k0 + 4);
      bfrag[0] = (_Float16)va.x; bfrag[1] = (_Float16)va.y;
      bfrag[2] = (_Float16)va.z; bfrag[3] = (_Float16)va.w;
      bfrag[4] = (_Float16)vb.x; bfrag[5] = (_Float16)vb.y;
      bfrag[6] = (_Float16)vb.z; bfrag[7] = (_Float16)vb.w;
    } else {
      float4 raw = *(const float4*)(Xh + node * HIDD + k0);  // 8 halves, 16B
      const __half2* hp = (const __half2*)&raw;
      float4 s0 = *(const float4*)(scsh + k0);
      float4 s1 = *(const float4*)(scsh + k0 + 4);
      float4 t0 = *(const float4*)(scsh + HIDD + k0);
      float4 t1 = *(const float4*)(scsh + HIDD + k0 + 4);
      float2 f0 = __half22float2(hp[0]);
      float2 f1 = __half22float2(hp[1]);
      float2 f2 = __half22float2(hp[2]);
      float2 f3 = __half22float2(hp[3]);
      bfrag[0] = (_Float16)bnelu1(f0.x, s0.x, t0.x);
      bfrag[1] = (_Float16)bnelu1(f0.y, s0.y, t0.y);
      bfrag[2] = (_Float16)bnelu1(f1.x, s0.z, t0.z);
      bfrag[3] = (_Float16)bnelu1(f1.y, s0.w, t0.w);
      bfrag[4] = (_Float16)bnelu1(f2.x, s1.x, t1.x);
      bfrag[5] = (_Float16)bnelu1(f2.y, s1.y, t1.y);
      bfrag[6] = (_Float16)bnelu1(f3.x, s1.z, t1.z);
      bfrag[7] = (_Float16)bnelu1(f3.y, s1.w, t1.w);
    }
#pragma unroll
    for (int c = 0; c < 8; ++c) {
      f16x8 afrag = *(const f16x8*)(Wp + (((c * 4 + ks) * 64 + lane) << 3));
      acc[c] = __builtin_amdgcn_mfma_f32_16x16x32_f16(afrag, bfrag, acc[c], 0, 0, 0);
    }
  }
  float es_p[4] = {0.f, 0.f, 0.f, 0.f};
  float ed_p[4] = {0.f, 0.f, 0.f, 0.f};
  __half* hrow = Hh + node * HIDD;
#pragma unroll
  for (int c = 0; c < 8; ++c) {
    int ch0 = c * 16 + kg * 4;
    __half2 h01 = __floats2half2_rn(acc[c][0], acc[c][1]);
    __half2 h23 = __floats2half2_rn(acc[c][2], acc[c][3]);
    union { __half2 h[2]; float2 f; } u;
    u.h[0] = h01; u.h[1] = h23;
    *(float2*)(hrow + ch0) = u.f;
    float4 av = *(const float4*)(asrc + ch0);
    float4 bv = *(const float4*)(adst + ch0);
    int hd = c >> 1;
    es_p[hd] += acc[c][0] * av.x + acc[c][1] * av.y + acc[c][2] * av.z + acc[c][3] * av.w;
    ed_p[hd] += acc[c][0] * bv.x + acc[c][1] * bv.y + acc[c][2] * bv.z + acc[c][3] * bv.w;
  }
#pragma unroll
  for (int hd = 0; hd < 4; ++hd) {
    es_p[hd] += __shfl_xor(es_p[hd], 16);
    es_p[hd] += __shfl_xor(es_p[hd], 32);
    ed_p[hd] += __shfl_xor(ed_p[hd], 16);
    ed_p[hd] += __shfl_xor(ed_p[hd], 32);
  }
  float es_o = (kg == 0) ? es_p[0] : (kg == 1) ? es_p[1] : (kg == 2) ? es_p[2] : es_p[3];
  float ed_o = (kg == 0) ? ed_p[0] : (kg == 1) ? ed_p[1] : (kg == 2) ? ed_p[2] : ed_p[3];
  esrc[node * 4 + kg] = es_o * LOG2E;
  edst[node * 4 + kg] = ed_o * LOG2E;
}

// one wave per dst node; lane owns channels 2l,2l+1 (head = l>>4).
// 8-wide edge batching, 32-bit addressing, exp2 weights. f16 output.
__global__ __launch_bounds__(256) void agg_kernel(const __half2* __restrict__ Hh,
                                                  const float* __restrict__ esrc,
                                                  const float* __restrict__ edst,
                                                  const int* __restrict__ rowptr,
                                                  const int* __restrict__ colb,
                                                  const float* __restrict__ bias,
                                                  __half* __restrict__ outh) {
  int wid = (blockIdx.x * 256 + threadIdx.x) >> 6;
  int lane = threadIdx.x & 63;
  if (wid >= NN) return;
  int hd = lane >> 4;
  float ed = edst[wid * 4 + hd];
  int e0 = rowptr[wid], e1 = rowptr[wid + 1];
  float den = 0.f, ax = 0.f, ay = 0.f;
  int e = e0;
  for (; e + 8 <= e1; e += 8) {
    int s[8];
#pragma unroll
    for (int j = 0; j < 8; ++j) s[j] = colb[e + j];
    float es[8];
    __half2 hv[8];
#pragma unroll
    for (int j = 0; j < 8; ++j) {
      es[j] = esrc[s[j] * 4 + hd];
      hv[j] = Hh[s[j] * 64 + lane];
    }
#pragma unroll
    for (int j = 0; j < 8; ++j) {
      float z = es[j] + ed;
      z = fmaxf(z, NEG_SLOPE * z);
      float w = exp2f(z);
      float2 f = __half22float2(hv[j]);
      den += w; ax += w * f.x; ay += w * f.y;
    }
  }
  for (; e + 4 <= e1; e += 4) {
    int s[4];
#pragma unroll
    for (int j = 0; j < 4; ++j) s[j] = colb[e + j];
    float es[4];
    __half2 hv[4];
#pragma unroll
    for (int j = 0; j < 4; ++j) {
      es[j] = esrc[s[j] * 4 + hd];
      hv[j] = Hh[s[j] * 64 + lane];
    }
#pragma unroll
    for (int j = 0; j < 4; ++j) {
      float z = es[j] + ed;
      z = fmaxf(z, NEG_SLOPE * z);
      float w = exp2f(z);
      float2 f = __half22float2(hv[j]);
      den += w; ax += w * f.x; ay += w * f.y;
    }
  }
  for (; e < e1; ++e) {
    int src = colb[e];
    float esv = esrc[src * 4 + hd];
    __half2 hvv = Hh[src * 64 + lane];
    float z = esv + ed;
    z = fmaxf(z, NEG_SLOPE * z);
    float w = exp2f(z);
    float2 f = __half22float2(hvv);
    den += w; ax += w * f.x; ay += w * f.y;
  }
  float inv = 1.f / (den + 1e-16f);
  int c = 2 * lane;
  float vx = ax * inv + bias[c];
  float vy = ay * inv + bias[c + 1];
  ((__half2*)outh)[wid * 64 + lane] = __floats2half2_rn(vx, vy);
}

__global__ __launch_bounds__(256) void bnstat_kernel(const __half* __restrict__ X,
                                                     float* __restrict__ stat) {
  __shared__ float sh[256];
  int tid = threadIdx.x;
  int c = tid & 127;
  int half = tid >> 7;
  float s = 0.f, q = 0.f;
  for (int r = blockIdx.x * 2 + half; r < NN; r += gridDim.x * 2) {
    float v = __half2float(X[r * HIDD + c]);
    s += v;
    q += v * v;
  }
  sh[tid] = s;
  __syncthreads();
  if (tid < 128) atomicAdd(&stat[c], s + sh[tid + 128]);
  __syncthreads();
  sh[tid] = q;
  __syncthreads();
  if (tid < 128) atomicAdd(&stat[128 + c], q + sh[tid + 128]);
}

__global__ void gbound_kernel(const int* __restrict__ batch, int* __restrict__ gstart) {
  int i = blockIdx.x * blockDim.x + threadIdx.x;
  if (i >= NN) return;
  int cur = batch[i];
  int prev = (i == 0) ? -1 : batch[i - 1];
  for (int g = prev + 1; g <= cur; ++g) gstart[g] = i;
  if (i == NN - 1) {
    for (int g = cur + 1; g <= GG; ++g) gstart[g] = NN;
  }
}

// fused: segmented mean pool (BN+ELU inline) + 2-layer MLP head
__global__ __launch_bounds__(128) void poolhead_kernel(const __half* __restrict__ X,
                                                       const int* __restrict__ gstart,
                                                       const float* __restrict__ scsh,
                                                       const float* __restrict__ w1,
                                                       const float* __restrict__ b1,
                                                       const float* __restrict__ w2,
                                                       const float* __restrict__ b2,
                                                       float* __restrict__ out) {
  __shared__ float pl[HIDD];
  int g = blockIdx.x;
  int c = threadIdx.x;
  float scale = scsh[c];
  float shift = scsh[128 + c];
  int n0 = gstart[g], n1 = gstart[g + 1];
  float s = 0.f;
  for (int n = n0; n < n1; ++n)
    s += bnelu1(__half2float(X[n * HIDD + c]), scale, shift);
  float inv = (n1 > n0) ? 1.f / (float)(n1 - n0) : 0.f;
  pl[c] = s * inv;
  __syncthreads();
  if (c < 64) {
    float acc = b1[c];
#pragma unroll 4
    for (int k = 0; k < HIDD; ++k) acc += pl[k] * w1[k * 64 + c];
    acc = fmaxf(acc, 0.f);
    float v = acc * w2[c];
#pragma unroll
    for (int off = 32; off > 0; off >>= 1) v += __shfl_down(v, off);
    if (c == 0) out[g] = v + b2[0];
  }
}

extern "C" void kernel_launch(void* const* d_in, const int* in_sizes, int n_in,
                              void* d_out, int out_size, void* d_ws, size_t ws_size,
                              hipStream_t stream) {
  const float* x    = (const float*)d_in[0];
  const int* ei     = (const int*)d_in[1];
  const int* batch  = (const int*)d_in[2];
  const float* Ws   = (const float*)d_in[3];
  const float* asrc = (const float*)d_in[4];
  const float* adst = (const float*)d_in[5];
  const float* bias = (const float*)d_in[6];
  const float* gam  = (const float*)d_in[7];
  const float* bet  = (const float*)d_in[8];
  const float* w1   = (const float*)d_in[9];
  const float* b1   = (const float*)d_in[10];
  const float* w2   = (const float*)d_in[11];
  const float* b2   = (const float*)d_in[12];
  float* out = (float*)d_out;

  char* wp = (char*)d_ws;
  auto carve = [&](size_t bytes) -> char* {
    char* p = wp;
    wp += (bytes + 255) & ~(size_t)255;
    return p;
  };
  __half* B     = (__half*)carve((size_t)NN * HIDD * 2);
  __half* Hh    = (__half*)carve((size_t)NN * HIDD * 2);
  _Float16* Wp  = (_Float16*)carve((size_t)3 * HIDD * HIDD * 2);
  float* scsh   = (float*)carve((size_t)3 * 256 * 4);
  float* esrc   = (float*)carve((size_t)NN * NHEAD * 4);
  float* edst   = (float*)carve((size_t)NN * NHEAD * 4);
  int* rowptr   = (int*)carve((size_t)(NN + 1) * 4);
  int* colb     = (int*)carve((size_t)EPTOT * 4);
  unsigned long long* pairs = (unsigned long long*)carve((size_t)EPTOT * 8);
  int* bcur     = (int*)carve((size_t)NBUK * 4);
  int* bsum     = (int*)carve((size_t)NB * 4);
  int* boff     = (int*)carve((size_t)NB * 4);
  int* gstart   = (int*)carve((size_t)(GG + 1) * 4);
  char* z0 = wp;
  int* deg      = (int*)carve((size_t)NN * 4);
  float* stats  = (float*)carve(768 * 4);
  int zcount = (int)((wp - z0) / 4);

  zero_kernel<<<(zcount + 255) / 256, 256, 0, stream>>>((float*)z0, zcount);
  prepack_kernel<<<24, 256, 0, stream>>>(Ws, Wp);
  count_kernel<<<(EPTOT + 255) / 256, 256, 0, stream>>>(ei, deg);
  degsum_kernel<<<NB, 256, 0, stream>>>(deg, bsum);
  scanb_kernel<<<1, 256, 0, stream>>>(bsum, boff, rowptr, bcur);
  rowptr_kernel<<<NB, 256, 0, stream>>>(deg, boff, rowptr);
  partA_kernel<<<(EPTOT + PCHUNK - 1) / PCHUNK, 256, 0, stream>>>(ei, bcur, pairs);
  partB_kernel<<<NBUK, 512, 0, stream>>>(pairs, rowptr, colb);
  gbound_kernel<<<(NN + 255) / 256, 256, 0, stream>>>(batch, gstart);

  for (int l = 0; l < 3; ++l) {
    const float* sc_prev = (l == 0) ? nullptr : scsh + (l - 1) * 256;
    const float* xf = (l == 0) ? x : nullptr;
    const __half* xh = (l == 0) ? nullptr : B;
    gemm_mfma_kernel<<<(NTILE + 3) / 4, 256, 0, stream>>>(
        xf, xh, Wp + (size_t)l * HIDD * HIDD, sc_prev,
        asrc + l * NHEAD * 32, adst + l * NHEAD * 32, Hh, esrc, edst);
    agg_kernel<<<(NN * 64 + 255) / 256, 256, 0, stream>>>(
        (const __half2*)Hh, esrc, edst, rowptr, colb, bias + l * HIDD, B);
    bnstat_kernel<<<1024, 256, 0, stream>>>(B, stats + l * 256);
    bnfinal_kernel<<<1, 128, 0, stream>>>(stats + l * 256, gam + l * HIDD,
                                          bet + l * HIDD, scsh + l * 256);
  }
  poolhead_kernel<<<GG, 128, 0, stream>>>(B, gstart, scsh + 2 * 256, w1, b1, w2, b2, out);
}